// Round 1
// baseline (814.784 us; speedup 1.0000x reference)
//
#include <hip/hip_runtime.h>

#define S_LEN 2048
#define HIDN  2560
#define HQ_N  8
#define HKV_N 4
#define HD_N  256
#define NQKV  4096   // HQ*HD + 2*HKV*HD
#define MROWS 4096   // B*S

typedef __attribute__((ext_vector_type(8))) short bf16x8;
typedef __attribute__((ext_vector_type(4))) float f32x4;
typedef __attribute__((ext_vector_type(4))) unsigned short u16x4;

static __device__ __forceinline__ float bf2f(unsigned short u) {
  unsigned int x = ((unsigned int)u) << 16;
  return __builtin_bit_cast(float, x);
}
static __device__ __forceinline__ unsigned short f2bf(float f) {
  unsigned int u = __builtin_bit_cast(unsigned int, f);
  u += 0x7fffu + ((u >> 16) & 1u);
  return (unsigned short)(u >> 16);
}

// ---------------- fp32 -> bf16 cast (vectorized x4) ----------------
__global__ void cvt_kernel(const float* __restrict__ src,
                           unsigned short* __restrict__ dst, int n4) {
  int i = blockIdx.x * 256 + threadIdx.x;
  if (i >= n4) return;
  f32x4 v = ((const f32x4*)src)[i];
  u16x4 o;
  o[0] = f2bf(v[0]); o[1] = f2bf(v[1]); o[2] = f2bf(v[2]); o[3] = f2bf(v[3]);
  ((u16x4*)dst)[i] = o;
}

// ---------------- C[m][n] = sum_k A[m][k] * B[n][k]  (both bf16 row-major, K-contig) ----
// block: 256 thr = 4 waves (2x2), wave tile 64x64, block tile 128x128.
template <int OUT_BF16>
__global__ __launch_bounds__(256) void gemm_tn(const unsigned short* __restrict__ A,
                                               const unsigned short* __restrict__ B,
                                               void* __restrict__ C,
                                               int M, int N, int K) {
  const int lane = threadIdx.x & 63;
  const int w = threadIdx.x >> 6;
  const int r = lane & 15, g = lane >> 4;
  const int brow = blockIdx.y * 128 + (w >> 1) * 64;
  const int bcol = blockIdx.x * 128 + (w & 1) * 64;
  const unsigned short* pa[4];
  const unsigned short* pb[4];
#pragma unroll
  for (int i = 0; i < 4; i++) {
    pa[i] = A + (size_t)(brow + i * 16 + r) * K + g * 8;
    pb[i] = B + (size_t)(bcol + i * 16 + r) * K + g * 8;
  }
  f32x4 acc[4][4];
#pragma unroll
  for (int i = 0; i < 4; i++)
#pragma unroll
    for (int j = 0; j < 4; j++) acc[i][j] = (f32x4){0.f, 0.f, 0.f, 0.f};

  for (int k0 = 0; k0 < K; k0 += 32) {
    bf16x8 af[4], bfr[4];
#pragma unroll
    for (int i = 0; i < 4; i++) af[i] = *(const bf16x8*)(pa[i] + k0);
#pragma unroll
    for (int i = 0; i < 4; i++) bfr[i] = *(const bf16x8*)(pb[i] + k0);
#pragma unroll
    for (int i = 0; i < 4; i++)
#pragma unroll
      for (int j = 0; j < 4; j++)
        acc[i][j] = __builtin_amdgcn_mfma_f32_16x16x32_bf16(af[i], bfr[j], acc[i][j], 0, 0, 0);
  }
#pragma unroll
  for (int i = 0; i < 4; i++)
#pragma unroll
    for (int j = 0; j < 4; j++) {
      int col = bcol + j * 16 + r;
#pragma unroll
      for (int e = 0; e < 4; e++) {
        int row = brow + i * 16 + g * 4 + e;
        if (OUT_BF16)
          ((unsigned short*)C)[(size_t)row * N + col] = f2bf(acc[i][j][e]);
        else
          ((float*)C)[(size_t)row * N + col] = acc[i][j][e];
      }
    }
}

// ---------------- fused RMSNorm (+weight) + RoPE, writes q/k [b][h][s][d], v^T [b][kvh][d][s]
__global__ __launch_bounds__(256) void rms_rope_kernel(
    const unsigned short* __restrict__ qkv, const float* __restrict__ cosb,
    const float* __restrict__ sinb, const float* __restrict__ qw,
    const float* __restrict__ kw, unsigned short* __restrict__ qo,
    unsigned short* __restrict__ ko, unsigned short* __restrict__ vT) {
  int wid = (blockIdx.x * 256 + threadIdx.x) >> 6;
  int lane = threadIdx.x & 63;
  int row = wid >> 4;   // 0..4095 (= b*2048 + s)
  int unit = wid & 15;  // 0..7 q heads, 8..11 k heads, 12..15 v heads
  int b = row >> 11, s = row & 2047;
  int d0 = lane * 4;
  const unsigned short* x = qkv + (size_t)row * NQKV + unit * HD_N + d0;
  u16x4 xb = *(const u16x4*)x;
  float v[4];
#pragma unroll
  for (int j = 0; j < 4; j++) v[j] = bf2f(xb[j]);
  float ss = v[0] * v[0] + v[1] * v[1] + v[2] * v[2] + v[3] * v[3];
#pragma unroll
  for (int off = 32; off >= 1; off >>= 1) ss += __shfl_xor(ss, off);
  float inv = 1.0f / sqrtf(ss * (1.0f / 256.0f) + 1e-6f);

  if (unit >= 12) {  // v: norm only, store transposed [d][s]
    int hv = unit - 12;
    unsigned short* dst = vT + (size_t)(b * HKV_N + hv) * HD_N * S_LEN;
#pragma unroll
    for (int j = 0; j < 4; j++) dst[(size_t)(d0 + j) * S_LEN + s] = f2bf(v[j] * inv);
    return;
  }
  const float* wv = (unit < 8) ? qw : kw;
  f32x4 wl = *(const f32x4*)(wv + d0);
  float y[4];
#pragma unroll
  for (int j = 0; j < 4; j++) y[j] = v[j] * inv * wl[j];
  float yp[4];
#pragma unroll
  for (int j = 0; j < 4; j++) yp[j] = __shfl_xor(y[j], 32);  // element at d ^ 128
  f32x4 cv = *(const f32x4*)(cosb + (size_t)row * HD_N + d0);
  f32x4 sv = *(const f32x4*)(sinb + (size_t)row * HD_N + d0);
  u16x4 out;
#pragma unroll
  for (int j = 0; j < 4; j++) {
    float rot = (d0 < 128) ? -yp[j] : yp[j];
    out[j] = f2bf(y[j] * cv[j] + rot * sv[j]);
  }
  unsigned short* dst;
  if (unit < 8)
    dst = qo + ((size_t)(b * HQ_N + unit) * S_LEN + s) * HD_N + d0;
  else
    dst = ko + ((size_t)(b * HKV_N + (unit - 8)) * S_LEN + s) * HD_N + d0;
  *(u16x4*)dst = out;
}

// ---------------- flash attention, 1 wave per (b,h,16 q-rows), sliding window ----------
__global__ __launch_bounds__(64) void attn_kernel(const unsigned short* __restrict__ qb,
                                                  const unsigned short* __restrict__ kb,
                                                  const unsigned short* __restrict__ vT,
                                                  unsigned short* __restrict__ attn) {
  const int lane = threadIdx.x & 63;
  const int r = lane & 15, g = lane >> 4;
  const int blk = blockIdx.x;
  const int qt = blk & 127;
  const int h = (blk >> 7) & 7;
  const int b = blk >> 10;
  const int kvh = h >> 1;
  const int q0 = qt * 16;
  const int qi = q0 + r;  // this lane's q-row (column of S^T / O^T)
  const unsigned short* qbase = qb + ((size_t)(b * HQ_N + h) * S_LEN + q0) * HD_N;
  const unsigned short* kbase = kb + (size_t)(b * HKV_N + kvh) * S_LEN * HD_N;
  const unsigned short* vbase = vT + (size_t)(b * HKV_N + kvh) * HD_N * S_LEN;

  bf16x8 qf[8];
#pragma unroll
  for (int c = 0; c < 8; c++)
    qf[c] = *(const bf16x8*)(qbase + (size_t)r * HD_N + c * 32 + g * 8);

  f32x4 o[16];
#pragma unroll
  for (int i = 0; i < 16; i++) o[i] = (f32x4){0.f, 0.f, 0.f, 0.f};
  float m = -1e30f, lsum = 0.0f;
  const float sc2 = 0.0625f * 1.4426950408889634f;  // HD^-0.5 * log2(e)

  int lo = q0 - 1023; if (lo < 0) lo = 0; lo &= ~31;
  for (int key0 = lo; key0 <= q0 + 15; key0 += 32) {
    f32x4 st0 = (f32x4){0.f, 0.f, 0.f, 0.f}, st1 = (f32x4){0.f, 0.f, 0.f, 0.f};
#pragma unroll
    for (int c = 0; c < 8; c++) {  // S^T = K . Q^T over HD
      bf16x8 kf0 = *(const bf16x8*)(kbase + (size_t)(key0 + r) * HD_N + c * 32 + g * 8);
      bf16x8 kf1 = *(const bf16x8*)(kbase + (size_t)(key0 + 16 + r) * HD_N + c * 32 + g * 8);
      st0 = __builtin_amdgcn_mfma_f32_16x16x32_bf16(kf0, qf[c], st0, 0, 0, 0);
      st1 = __builtin_amdgcn_mfma_f32_16x16x32_bf16(kf1, qf[c], st1, 0, 0, 0);
    }
    float p[2][4];
    float pm = -3e30f;
#pragma unroll
    for (int t = 0; t < 2; t++)
#pragma unroll
      for (int e = 0; e < 4; e++) {
        int key = key0 + t * 16 + 4 * g + e;
        float sv = (t == 0 ? st0[e] : st1[e]) * sc2;
        sv = (key <= qi && key > qi - 1024) ? sv : -2e30f;  // window mask
        p[t][e] = sv;
        pm = fmaxf(pm, sv);
      }
    pm = fmaxf(pm, __shfl_xor(pm, 16));
    pm = fmaxf(pm, __shfl_xor(pm, 32));
    float newm = fmaxf(m, pm);
    float f = exp2f(m - newm);
    m = newm;
    float ps = 0.0f;
#pragma unroll
    for (int t = 0; t < 2; t++)
#pragma unroll
      for (int e = 0; e < 4; e++) {
        float pe = exp2f(p[t][e] - m);
        p[t][e] = pe;
        ps += pe;
      }
    ps += __shfl_xor(ps, 16);
    ps += __shfl_xor(ps, 32);
    lsum = lsum * f + ps;
#pragma unroll
    for (int i = 0; i < 16; i++) {
      o[i][0] *= f; o[i][1] *= f; o[i][2] *= f; o[i][3] *= f;
    }
    // build P^T B-fragment: lane needs P^T[key0+8g+e2][qrow r]
    short pk[8];
#pragma unroll
    for (int e2 = 0; e2 < 8; e2++) {
      int srcl = r + 16 * (2 * (g & 1) + (e2 >> 2));
      float a0 = __shfl(p[0][e2 & 3], srcl);
      float a1 = __shfl(p[1][e2 & 3], srcl);
      pk[e2] = (short)f2bf((g < 2) ? a0 : a1);
    }
    bf16x8 pf = {pk[0], pk[1], pk[2], pk[3], pk[4], pk[5], pk[6], pk[7]};
#pragma unroll
    for (int c2 = 0; c2 < 16; c2++) {  // O^T += V^T . P^T
      bf16x8 vf = *(const bf16x8*)(vbase + (size_t)(c2 * 16 + r) * S_LEN + key0 + g * 8);
      o[c2] = __builtin_amdgcn_mfma_f32_16x16x32_bf16(vf, pf, o[c2], 0, 0, 0);
    }
  }
  float linv = 1.0f / lsum;
  unsigned short* arow = attn + ((size_t)(b * S_LEN) + q0 + r) * (HQ_N * HD_N) + h * HD_N;
#pragma unroll
  for (int c2 = 0; c2 < 16; c2++) {
    unsigned int w0 = (unsigned)f2bf(o[c2][0] * linv) | ((unsigned)f2bf(o[c2][1] * linv) << 16);
    unsigned int w1 = (unsigned)f2bf(o[c2][2] * linv) | ((unsigned)f2bf(o[c2][3] * linv) << 16);
    *(unsigned int*)(arow + c2 * 16 + 4 * g) = w0;
    *(unsigned int*)(arow + c2 * 16 + 4 * g + 2) = w1;
  }
}

extern "C" void kernel_launch(void* const* d_in, const int* in_sizes, int n_in,
                              void* d_out, int out_size, void* d_ws, size_t ws_size,
                              hipStream_t stream) {
  const float* hid  = (const float*)d_in[0];
  const float* cosb = (const float*)d_in[1];
  const float* sinb = (const float*)d_in[2];
  const float* Wq   = (const float*)d_in[4];
  const float* Wk   = (const float*)d_in[5];
  const float* Wv   = (const float*)d_in[6];
  const float* Wo   = (const float*)d_in[7];
  const float* qw   = (const float*)d_in[8];
  const float* kw   = (const float*)d_in[9];

  char* ws = (char*)d_ws;
  unsigned short* Xbf   = (unsigned short*)(ws + 0);            // 4096x2560 bf16  (20,971,520 B)
  unsigned short* Wcat  = (unsigned short*)(ws + 20971520);     // 4096x2560 bf16
  unsigned short* Wob   = (unsigned short*)(ws + 41943040);     // 2560x2048 bf16  (10,485,760 B)
  unsigned short* QKV   = (unsigned short*)(ws + 52428800);     // 4096x4096 bf16  (33,554,432 B)
  unsigned short* qbuf  = (unsigned short*)(ws + 85983232);     // 2*8*2048*256    (16,777,216 B)
  unsigned short* kbuf  = (unsigned short*)(ws + 102760448);    // 2*4*2048*256    ( 8,388,608 B)
  unsigned short* vTbuf = (unsigned short*)(ws + 111149056);    // 2*4*256*2048    ( 8,388,608 B)
  unsigned short* attnb = (unsigned short*)(ws + 119537664);    // 4096x2048 bf16  (16,777,216 B)
  // total: 136,314,880 B

  // 1) casts
  cvt_kernel<<<10240, 256, 0, stream>>>(hid, Xbf, 2621440);
  cvt_kernel<<<5120, 256, 0, stream>>>(Wq, Wcat, 1310720);
  cvt_kernel<<<2560, 256, 0, stream>>>(Wk, Wcat + 5242880, 655360);
  cvt_kernel<<<2560, 256, 0, stream>>>(Wv, Wcat + 7864320, 655360);
  cvt_kernel<<<5120, 256, 0, stream>>>(Wo, Wob, 1310720);
  // 2) fused QKV projection: QKV = X @ Wcat^T
  gemm_tn<1><<<dim3(32, 32), 256, 0, stream>>>(Xbf, Wcat, QKV, 4096, 4096, 2560);
  // 3) RMSNorm + RoPE
  rms_rope_kernel<<<16384, 256, 0, stream>>>(QKV, cosb, sinb, qw, kw, qbuf, kbuf, vTbuf);
  // 4) sliding-window flash attention
  attn_kernel<<<2048, 64, 0, stream>>>(qbuf, kbuf, vTbuf, attnb);
  // 5) output projection: d_out = attn @ Wo^T (fp32 out)
  gemm_tn<0><<<dim3(20, 32), 256, 0, stream>>>(attnb, Wob, (float*)d_out, 4096, 2560, 2048);
}

// Round 2
// 548.413 us; speedup vs baseline: 1.4857x; 1.4857x over previous
//
#include <hip/hip_runtime.h>

#define S_LEN 2048
#define HIDN  2560
#define HQ_N  8
#define HKV_N 4
#define HD_N  256
#define NQKV  4096   // HQ*HD + 2*HKV*HD
#define MROWS 4096   // B*S

typedef __attribute__((ext_vector_type(8))) short bf16x8;
typedef __attribute__((ext_vector_type(4))) float f32x4;
typedef __attribute__((ext_vector_type(4))) unsigned short u16x4;

typedef const __attribute__((address_space(1))) unsigned int* gas_t;
typedef __attribute__((address_space(3))) unsigned int* las_t;
#define GLDS16(gp, lp) __builtin_amdgcn_global_load_lds((gas_t)(const void*)(gp), \
                                                        (las_t)(void*)(lp), 16, 0, 0)

static __device__ __forceinline__ float bf2f(unsigned short u) {
  unsigned int x = ((unsigned int)u) << 16;
  return __builtin_bit_cast(float, x);
}
static __device__ __forceinline__ unsigned short f2bf(float f) {
  unsigned int u = __builtin_bit_cast(unsigned int, f);
  u += 0x7fffu + ((u >> 16) & 1u);
  return (unsigned short)(u >> 16);
}

// ---------------- fp32 -> bf16 cast (vectorized x4) ----------------
__global__ void cvt_kernel(const float* __restrict__ src,
                           unsigned short* __restrict__ dst, int n4) {
  int i = blockIdx.x * 256 + threadIdx.x;
  if (i >= n4) return;
  f32x4 v = ((const f32x4*)src)[i];
  u16x4 o;
  o[0] = f2bf(v[0]); o[1] = f2bf(v[1]); o[2] = f2bf(v[2]); o[3] = f2bf(v[3]);
  ((u16x4*)dst)[i] = o;
}

// ---------------- C[m][n] = sum_k A[m][k]*B[n][k], m97-style LDS-staged GEMM ----------
// 128x128 block tile, BK=32, 4 waves (2x2), wave tile 64x64 (4x4 of 16x16x32 MFMA).
// Staging: global_load_lds width 16, linear LDS [128][32] bf16 per operand (8 KB each).
template <int OUT_BF16>
__global__ __launch_bounds__(256) void gemm_lds(const unsigned short* __restrict__ A,
                                                const unsigned short* __restrict__ B,
                                                void* __restrict__ C,
                                                int M, int N, int K) {
  __shared__ unsigned short lA[128 * 32];
  __shared__ unsigned short lB[128 * 32];
  const int lane = threadIdx.x & 63;
  const int w = threadIdx.x >> 6;
  const int r = lane & 15, g = lane >> 4;
  const int brow = blockIdx.y * 128;
  const int bcol = blockIdx.x * 128;
  const int wrow = (w >> 1) * 64, wcol = (w & 1) * 64;

  // staging: wave w covers tile rows [w*32, w*32+32), two 16-row chunks of 1024 B
  const int srow = w * 32 + (lane >> 2);
  const int scol = (lane & 3) * 8;
  const unsigned short* gA = A + (size_t)(brow + srow) * K + scol;
  const unsigned short* gB = B + (size_t)(bcol + srow) * K + scol;
  unsigned short* lAw = lA + w * 1024;  // +512 for second chunk (elements)
  unsigned short* lBw = lB + w * 1024;
  const size_t kstep16 = (size_t)16 * K;

  // compute-phase LDS fragment offsets (elements)
  int aoff[4], boff[4];
#pragma unroll
  for (int i = 0; i < 4; i++) {
    aoff[i] = (wrow + i * 16 + r) * 32 + g * 8;
    boff[i] = (wcol + i * 16 + r) * 32 + g * 8;
  }

  f32x4 acc[4][4];
#pragma unroll
  for (int i = 0; i < 4; i++)
#pragma unroll
    for (int j = 0; j < 4; j++) acc[i][j] = (f32x4){0.f, 0.f, 0.f, 0.f};

  for (int k0 = 0; k0 < K; k0 += 32) {
    __syncthreads();  // previous compute done before overwrite
    GLDS16(gA + k0, lAw);
    GLDS16(gA + k0 + kstep16, lAw + 512);
    GLDS16(gB + k0, lBw);
    GLDS16(gB + k0 + kstep16, lBw + 512);
    __syncthreads();  // vmcnt(0) drain: tile resident
    bf16x8 af[4], bfr[4];
#pragma unroll
    for (int i = 0; i < 4; i++) af[i] = *(const bf16x8*)(lA + aoff[i]);
#pragma unroll
    for (int j = 0; j < 4; j++) bfr[j] = *(const bf16x8*)(lB + boff[j]);
#pragma unroll
    for (int i = 0; i < 4; i++)
#pragma unroll
      for (int j = 0; j < 4; j++)
        acc[i][j] = __builtin_amdgcn_mfma_f32_16x16x32_bf16(af[i], bfr[j], acc[i][j], 0, 0, 0);
  }

#pragma unroll
  for (int i = 0; i < 4; i++)
#pragma unroll
    for (int j = 0; j < 4; j++) {
      int col = bcol + wcol + j * 16 + r;
#pragma unroll
      for (int e = 0; e < 4; e++) {
        int row = brow + wrow + i * 16 + g * 4 + e;
        if (OUT_BF16)
          ((unsigned short*)C)[(size_t)row * N + col] = f2bf(acc[i][j][e]);
        else
          ((float*)C)[(size_t)row * N + col] = acc[i][j][e];
      }
    }
}

// ---------------- fused RMSNorm (+weight) + RoPE, writes q/k [b][h][s][d], v^T [b][kvh][d][s]
__global__ __launch_bounds__(256) void rms_rope_kernel(
    const unsigned short* __restrict__ qkv, const float* __restrict__ cosb,
    const float* __restrict__ sinb, const float* __restrict__ qw,
    const float* __restrict__ kw, unsigned short* __restrict__ qo,
    unsigned short* __restrict__ ko, unsigned short* __restrict__ vT) {
  int wid = (blockIdx.x * 256 + threadIdx.x) >> 6;
  int lane = threadIdx.x & 63;
  int row = wid >> 4;   // 0..4095 (= b*2048 + s)
  int unit = wid & 15;  // 0..7 q heads, 8..11 k heads, 12..15 v heads
  int b = row >> 11, s = row & 2047;
  int d0 = lane * 4;
  const unsigned short* x = qkv + (size_t)row * NQKV + unit * HD_N + d0;
  u16x4 xb = *(const u16x4*)x;
  float v[4];
#pragma unroll
  for (int j = 0; j < 4; j++) v[j] = bf2f(xb[j]);
  float ss = v[0] * v[0] + v[1] * v[1] + v[2] * v[2] + v[3] * v[3];
#pragma unroll
  for (int off = 32; off >= 1; off >>= 1) ss += __shfl_xor(ss, off);
  float inv = 1.0f / sqrtf(ss * (1.0f / 256.0f) + 1e-6f);

  if (unit >= 12) {  // v: norm only, store transposed [d][s]
    int hv = unit - 12;
    unsigned short* dst = vT + (size_t)(b * HKV_N + hv) * HD_N * S_LEN;
#pragma unroll
    for (int j = 0; j < 4; j++) dst[(size_t)(d0 + j) * S_LEN + s] = f2bf(v[j] * inv);
    return;
  }
  const float* wv = (unit < 8) ? qw : kw;
  f32x4 wl = *(const f32x4*)(wv + d0);
  float y[4];
#pragma unroll
  for (int j = 0; j < 4; j++) y[j] = v[j] * inv * wl[j];
  float yp[4];
#pragma unroll
  for (int j = 0; j < 4; j++) yp[j] = __shfl_xor(y[j], 32);  // element at d ^ 128
  f32x4 cv = *(const f32x4*)(cosb + (size_t)row * HD_N + d0);
  f32x4 sv = *(const f32x4*)(sinb + (size_t)row * HD_N + d0);
  u16x4 out;
#pragma unroll
  for (int j = 0; j < 4; j++) {
    float rot = (d0 < 128) ? -yp[j] : yp[j];
    out[j] = f2bf(y[j] * cv[j] + rot * sv[j]);
  }
  unsigned short* dst;
  if (unit < 8)
    dst = qo + ((size_t)(b * HQ_N + unit) * S_LEN + s) * HD_N + d0;
  else
    dst = ko + ((size_t)(b * HKV_N + (unit - 8)) * S_LEN + s) * HD_N + d0;
  *(u16x4*)dst = out;
}

// ---------------- flash attention, 1 wave per (b,h,16 q-rows), sliding window ----------
__global__ __launch_bounds__(64) void attn_kernel(const unsigned short* __restrict__ qb,
                                                  const unsigned short* __restrict__ kb,
                                                  const unsigned short* __restrict__ vT,
                                                  unsigned short* __restrict__ attn) {
  const int lane = threadIdx.x & 63;
  const int r = lane & 15, g = lane >> 4;
  const int blk = blockIdx.x;
  const int qt = blk & 127;
  const int h = (blk >> 7) & 7;
  const int b = blk >> 10;
  const int kvh = h >> 1;
  const int q0 = qt * 16;
  const int qi = q0 + r;  // this lane's q-row (column of S^T / O^T)
  const unsigned short* qbase = qb + ((size_t)(b * HQ_N + h) * S_LEN + q0) * HD_N;
  const unsigned short* kbase = kb + (size_t)(b * HKV_N + kvh) * S_LEN * HD_N;
  const unsigned short* vbase = vT + (size_t)(b * HKV_N + kvh) * HD_N * S_LEN;

  bf16x8 qf[8];
#pragma unroll
  for (int c = 0; c < 8; c++)
    qf[c] = *(const bf16x8*)(qbase + (size_t)r * HD_N + c * 32 + g * 8);

  f32x4 o[16];
#pragma unroll
  for (int i = 0; i < 16; i++) o[i] = (f32x4){0.f, 0.f, 0.f, 0.f};
  float m = -1e30f, lsum = 0.0f;
  const float sc2 = 0.0625f * 1.4426950408889634f;  // HD^-0.5 * log2(e)

  int lo = q0 - 1023; if (lo < 0) lo = 0; lo &= ~31;
  for (int key0 = lo; key0 <= q0 + 15; key0 += 32) {
    f32x4 st0 = (f32x4){0.f, 0.f, 0.f, 0.f}, st1 = (f32x4){0.f, 0.f, 0.f, 0.f};
#pragma unroll
    for (int c = 0; c < 8; c++) {  // S^T = K . Q^T over HD
      bf16x8 kf0 = *(const bf16x8*)(kbase + (size_t)(key0 + r) * HD_N + c * 32 + g * 8);
      bf16x8 kf1 = *(const bf16x8*)(kbase + (size_t)(key0 + 16 + r) * HD_N + c * 32 + g * 8);
      st0 = __builtin_amdgcn_mfma_f32_16x16x32_bf16(kf0, qf[c], st0, 0, 0, 0);
      st1 = __builtin_amdgcn_mfma_f32_16x16x32_bf16(kf1, qf[c], st1, 0, 0, 0);
    }
    float p[2][4];
    float pm = -3e30f;
#pragma unroll
    for (int t = 0; t < 2; t++)
#pragma unroll
      for (int e = 0; e < 4; e++) {
        int key = key0 + t * 16 + 4 * g + e;
        float sv = (t == 0 ? st0[e] : st1[e]) * sc2;
        sv = (key <= qi && key > qi - 1024) ? sv : -2e30f;  // window mask
        p[t][e] = sv;
        pm = fmaxf(pm, sv);
      }
    pm = fmaxf(pm, __shfl_xor(pm, 16));
    pm = fmaxf(pm, __shfl_xor(pm, 32));
    float newm = fmaxf(m, pm);
    float f = exp2f(m - newm);
    m = newm;
    float ps = 0.0f;
#pragma unroll
    for (int t = 0; t < 2; t++)
#pragma unroll
      for (int e = 0; e < 4; e++) {
        float pe = exp2f(p[t][e] - m);
        p[t][e] = pe;
        ps += pe;
      }
    ps += __shfl_xor(ps, 16);
    ps += __shfl_xor(ps, 32);
    lsum = lsum * f + ps;
#pragma unroll
    for (int i = 0; i < 16; i++) {
      o[i][0] *= f; o[i][1] *= f; o[i][2] *= f; o[i][3] *= f;
    }
    // build P^T B-fragment: lane needs P^T[key0+8g+e2][qrow r]
    short pk[8];
#pragma unroll
    for (int e2 = 0; e2 < 8; e2++) {
      int srcl = r + 16 * (2 * (g & 1) + (e2 >> 2));
      float a0 = __shfl(p[0][e2 & 3], srcl);
      float a1 = __shfl(p[1][e2 & 3], srcl);
      pk[e2] = (short)f2bf((g < 2) ? a0 : a1);
    }
    bf16x8 pf = {pk[0], pk[1], pk[2], pk[3], pk[4], pk[5], pk[6], pk[7]};
#pragma unroll
    for (int c2 = 0; c2 < 16; c2++) {  // O^T += V^T . P^T
      bf16x8 vf = *(const bf16x8*)(vbase + (size_t)(c2 * 16 + r) * S_LEN + key0 + g * 8);
      o[c2] = __builtin_amdgcn_mfma_f32_16x16x32_bf16(vf, pf, o[c2], 0, 0, 0);
    }
  }
  float linv = 1.0f / lsum;
  unsigned short* arow = attn + ((size_t)(b * S_LEN) + q0 + r) * (HQ_N * HD_N) + h * HD_N;
#pragma unroll
  for (int c2 = 0; c2 < 16; c2++) {
    unsigned int w0 = (unsigned)f2bf(o[c2][0] * linv) | ((unsigned)f2bf(o[c2][1] * linv) << 16);
    unsigned int w1 = (unsigned)f2bf(o[c2][2] * linv) | ((unsigned)f2bf(o[c2][3] * linv) << 16);
    *(unsigned int*)(arow + c2 * 16 + 4 * g) = w0;
    *(unsigned int*)(arow + c2 * 16 + 4 * g + 2) = w1;
  }
}

extern "C" void kernel_launch(void* const* d_in, const int* in_sizes, int n_in,
                              void* d_out, int out_size, void* d_ws, size_t ws_size,
                              hipStream_t stream) {
  const float* hid  = (const float*)d_in[0];
  const float* cosb = (const float*)d_in[1];
  const float* sinb = (const float*)d_in[2];
  const float* Wq   = (const float*)d_in[4];
  const float* Wk   = (const float*)d_in[5];
  const float* Wv   = (const float*)d_in[6];
  const float* Wo   = (const float*)d_in[7];
  const float* qw   = (const float*)d_in[8];
  const float* kw   = (const float*)d_in[9];

  char* ws = (char*)d_ws;
  unsigned short* Xbf   = (unsigned short*)(ws + 0);            // 4096x2560 bf16  (20,971,520 B)
  unsigned short* Wcat  = (unsigned short*)(ws + 20971520);     // 4096x2560 bf16
  unsigned short* Wob   = (unsigned short*)(ws + 41943040);     // 2560x2048 bf16  (10,485,760 B)
  unsigned short* QKV   = (unsigned short*)(ws + 52428800);     // 4096x4096 bf16  (33,554,432 B)
  unsigned short* qbuf  = (unsigned short*)(ws + 85983232);     // 2*8*2048*256    (16,777,216 B)
  unsigned short* kbuf  = (unsigned short*)(ws + 102760448);    // 2*4*2048*256    ( 8,388,608 B)
  unsigned short* vTbuf = (unsigned short*)(ws + 111149056);    // 2*4*256*2048    ( 8,388,608 B)
  unsigned short* attnb = (unsigned short*)(ws + 119537664);    // 4096x2048 bf16  (16,777,216 B)
  // total: 136,314,880 B

  // 1) casts
  cvt_kernel<<<10240, 256, 0, stream>>>(hid, Xbf, 2621440);
  cvt_kernel<<<5120, 256, 0, stream>>>(Wq, Wcat, 1310720);
  cvt_kernel<<<2560, 256, 0, stream>>>(Wk, Wcat + 5242880, 655360);
  cvt_kernel<<<2560, 256, 0, stream>>>(Wv, Wcat + 7864320, 655360);
  cvt_kernel<<<5120, 256, 0, stream>>>(Wo, Wob, 1310720);
  // 2) fused QKV projection: QKV = X @ Wcat^T
  gemm_lds<1><<<dim3(32, 32), 256, 0, stream>>>(Xbf, Wcat, QKV, 4096, 4096, 2560);
  // 3) RMSNorm + RoPE
  rms_rope_kernel<<<16384, 256, 0, stream>>>(QKV, cosb, sinb, qw, kw, qbuf, kbuf, vTbuf);
  // 4) sliding-window flash attention
  attn_kernel<<<2048, 64, 0, stream>>>(qbuf, kbuf, vTbuf, attnb);
  // 5) output projection: d_out = attn @ Wo^T (fp32 out)
  gemm_lds<0><<<dim3(20, 32), 256, 0, stream>>>(attnb, Wob, (float*)d_out, 4096, 2560, 2048);
}

// Round 3
// 400.067 us; speedup vs baseline: 2.0366x; 1.3708x over previous
//
#include <hip/hip_runtime.h>

#define S_LEN 2048
#define HIDN  2560
#define HQ_N  8
#define HKV_N 4
#define HD_N  256
#define NQKV  4096   // HQ*HD + 2*HKV*HD
#define MROWS 4096   // B*S

typedef __attribute__((ext_vector_type(8))) short bf16x8;
typedef __attribute__((ext_vector_type(4))) float f32x4;
typedef __attribute__((ext_vector_type(4))) unsigned short u16x4;

typedef const __attribute__((address_space(1))) unsigned int* gas_t;
typedef __attribute__((address_space(3))) unsigned int* las_t;
#define GLDS16(gp, lp) __builtin_amdgcn_global_load_lds((gas_t)(const void*)(gp), \
                                                        (las_t)(void*)(lp), 16, 0, 0)

static __device__ __forceinline__ float bf2f(unsigned short u) {
  unsigned int x = ((unsigned int)u) << 16;
  return __builtin_bit_cast(float, x);
}
static __device__ __forceinline__ unsigned short f2bf(float f) {
  unsigned int u = __builtin_bit_cast(unsigned int, f);
  u += 0x7fffu + ((u >> 16) & 1u);
  return (unsigned short)(u >> 16);
}

// ---------------- fp32 -> bf16 cast (vectorized x4) ----------------
__global__ void cvt_kernel(const float* __restrict__ src,
                           unsigned short* __restrict__ dst, int n4) {
  int i = blockIdx.x * 256 + threadIdx.x;
  if (i >= n4) return;
  f32x4 v = ((const f32x4*)src)[i];
  u16x4 o;
  o[0] = f2bf(v[0]); o[1] = f2bf(v[1]); o[2] = f2bf(v[2]); o[3] = f2bf(v[3]);
  ((u16x4*)dst)[i] = o;
}

// ---------------- C[m][n] = sum_k A[m][k]*B[n][k], m97-style LDS-staged GEMM ----------
template <int OUT_BF16>
__global__ __launch_bounds__(256) void gemm_lds(const unsigned short* __restrict__ A,
                                                const unsigned short* __restrict__ B,
                                                void* __restrict__ C,
                                                int M, int N, int K) {
  __shared__ unsigned short lA[128 * 32];
  __shared__ unsigned short lB[128 * 32];
  const int lane = threadIdx.x & 63;
  const int w = threadIdx.x >> 6;
  const int r = lane & 15, g = lane >> 4;
  const int brow = blockIdx.y * 128;
  const int bcol = blockIdx.x * 128;
  const int wrow = (w >> 1) * 64, wcol = (w & 1) * 64;

  const int srow = w * 32 + (lane >> 2);
  const int scol = (lane & 3) * 8;
  const unsigned short* gA = A + (size_t)(brow + srow) * K + scol;
  const unsigned short* gB = B + (size_t)(bcol + srow) * K + scol;
  unsigned short* lAw = lA + w * 1024;
  unsigned short* lBw = lB + w * 1024;
  const size_t kstep16 = (size_t)16 * K;

  int aoff[4], boff[4];
#pragma unroll
  for (int i = 0; i < 4; i++) {
    aoff[i] = (wrow + i * 16 + r) * 32 + g * 8;
    boff[i] = (wcol + i * 16 + r) * 32 + g * 8;
  }

  f32x4 acc[4][4];
#pragma unroll
  for (int i = 0; i < 4; i++)
#pragma unroll
    for (int j = 0; j < 4; j++) acc[i][j] = (f32x4){0.f, 0.f, 0.f, 0.f};

  for (int k0 = 0; k0 < K; k0 += 32) {
    __syncthreads();
    GLDS16(gA + k0, lAw);
    GLDS16(gA + k0 + kstep16, lAw + 512);
    GLDS16(gB + k0, lBw);
    GLDS16(gB + k0 + kstep16, lBw + 512);
    __syncthreads();
    bf16x8 af[4], bfr[4];
#pragma unroll
    for (int i = 0; i < 4; i++) af[i] = *(const bf16x8*)(lA + aoff[i]);
#pragma unroll
    for (int j = 0; j < 4; j++) bfr[j] = *(const bf16x8*)(lB + boff[j]);
#pragma unroll
    for (int i = 0; i < 4; i++)
#pragma unroll
      for (int j = 0; j < 4; j++)
        acc[i][j] = __builtin_amdgcn_mfma_f32_16x16x32_bf16(af[i], bfr[j], acc[i][j], 0, 0, 0);
  }

#pragma unroll
  for (int i = 0; i < 4; i++)
#pragma unroll
    for (int j = 0; j < 4; j++) {
      int col = bcol + wcol + j * 16 + r;
#pragma unroll
      for (int e = 0; e < 4; e++) {
        int row = brow + wrow + i * 16 + g * 4 + e;
        if (OUT_BF16)
          ((unsigned short*)C)[(size_t)row * N + col] = f2bf(acc[i][j][e]);
        else
          ((float*)C)[(size_t)row * N + col] = acc[i][j][e];
      }
    }
}

// ---------------- fused RMSNorm (+weight) + RoPE ----------------
// q: [b][h][s][d] row-major bf16.
// k: per-32-key tiled slabs [b][kvh][kb=64][kr=32][32 slots of 8 elems], slot pre-swizzled:
//      slot' = (d>>3) ^ (kr&7)
// v: per-32-key tiled slabs [b][kvh][kb=64][d=256][4 slots of 8 keys], slot pre-swizzled:
//      slot' = (ks>>3) ^ ((d>>1)&3)
__global__ __launch_bounds__(256) void rms_rope_kernel(
    const unsigned short* __restrict__ qkv, const float* __restrict__ cosb,
    const float* __restrict__ sinb, const float* __restrict__ qw,
    const float* __restrict__ kw, unsigned short* __restrict__ qo,
    unsigned short* __restrict__ ko, unsigned short* __restrict__ vo) {
  int wid = (blockIdx.x * 256 + threadIdx.x) >> 6;
  int lane = threadIdx.x & 63;
  int row = wid >> 4;   // 0..4095 (= b*2048 + s)
  int unit = wid & 15;  // 0..7 q heads, 8..11 k heads, 12..15 v heads
  int b = row >> 11, s = row & 2047;
  int d0 = lane * 4;
  const unsigned short* x = qkv + (size_t)row * NQKV + unit * HD_N + d0;
  u16x4 xb = *(const u16x4*)x;
  float v[4];
#pragma unroll
  for (int j = 0; j < 4; j++) v[j] = bf2f(xb[j]);
  float ss = v[0] * v[0] + v[1] * v[1] + v[2] * v[2] + v[3] * v[3];
#pragma unroll
  for (int off = 32; off >= 1; off >>= 1) ss += __shfl_xor(ss, off);
  float inv = 1.0f / sqrtf(ss * (1.0f / 256.0f) + 1e-6f);

  int kb = s >> 5;
  if (unit >= 12) {  // v: norm only, tiled+swizzled
    int hv = unit - 12;
    int ks = s & 31;
    unsigned short* slab = vo + ((size_t)(b * HKV_N + hv) * 64 + kb) * 8192;
#pragma unroll
    for (int j = 0; j < 4; j++) {
      int d = d0 + j;
      int pos = d * 32 + (((ks >> 3) ^ ((d >> 1) & 3)) << 3) + (ks & 7);
      slab[pos] = f2bf(v[j] * inv);
    }
    return;
  }
  const float* wv = (unit < 8) ? qw : kw;
  f32x4 wl = *(const f32x4*)(wv + d0);
  float y[4];
#pragma unroll
  for (int j = 0; j < 4; j++) y[j] = v[j] * inv * wl[j];
  float yp[4];
#pragma unroll
  for (int j = 0; j < 4; j++) yp[j] = __shfl_xor(y[j], 32);  // element at d ^ 128
  f32x4 cv = *(const f32x4*)(cosb + (size_t)row * HD_N + d0);
  f32x4 sv = *(const f32x4*)(sinb + (size_t)row * HD_N + d0);
  u16x4 out;
#pragma unroll
  for (int j = 0; j < 4; j++) {
    float rot = (d0 < 128) ? -yp[j] : yp[j];
    out[j] = f2bf(y[j] * cv[j] + rot * sv[j]);
  }
  if (unit < 8) {
    unsigned short* dst = qo + ((size_t)(b * HQ_N + unit) * S_LEN + s) * HD_N + d0;
    *(u16x4*)dst = out;
  } else {
    int kv = unit - 8;
    int kr = s & 31;
    unsigned short* dst = ko + ((size_t)(b * HKV_N + kv) * 64 + kb) * 8192 + kr * 256 +
                          (((d0 >> 3) ^ (kr & 7)) << 3) + (d0 & 7);
    *(u16x4*)dst = out;
  }
}

// ---------------- flash attention: 4 waves/block, QBLK=64, K/V LDS double-buffered ------
__global__ __launch_bounds__(256) void attn_kernel(const unsigned short* __restrict__ qb,
                                                   const unsigned short* __restrict__ kb_,
                                                   const unsigned short* __restrict__ vb_,
                                                   unsigned short* __restrict__ attn) {
  __shared__ unsigned short kt[2][8192];
  __shared__ unsigned short vt[2][8192];
  const int lane = threadIdx.x & 63;
  const int w = threadIdx.x >> 6;
  const int r = lane & 15, g = lane >> 4;
  const int blk = blockIdx.x;
  const int qt = blk & 31;
  const int h = (blk >> 5) & 7;
  const int b = blk >> 8;
  const int kvh = h >> 1;
  const int q0 = qt * 64;
  const int qi = q0 + w * 16 + r;  // this lane's q-row
  const unsigned short* qbase = qb + ((size_t)(b * HQ_N + h) * S_LEN + q0 + w * 16) * HD_N;
  const unsigned short* kslabs = kb_ + (size_t)(b * HKV_N + kvh) * S_LEN * HD_N;
  const unsigned short* vslabs = vb_ + (size_t)(b * HKV_N + kvh) * S_LEN * HD_N;

  bf16x8 qf[8];
#pragma unroll
  for (int c = 0; c < 8; c++)
    qf[c] = *(const bf16x8*)(qbase + (size_t)r * HD_N + c * 32 + g * 8);

  f32x4 o[16];
#pragma unroll
  for (int i = 0; i < 16; i++) o[i] = (f32x4){0.f, 0.f, 0.f, 0.f};
  float m = -1e30f, lsum = 0.0f;
  const float sc2 = 0.0625f * 1.4426950408889634f;  // HD^-0.5 * log2(e)

  int lo = q0 - 1023; if (lo < 0) lo = 0; lo &= ~31;
  const int hiend = q0 + 64;

  // prologue stage
  {
    const unsigned short* ks = kslabs + (size_t)(lo >> 5) * 8192 + w * 2048;
    const unsigned short* vs = vslabs + (size_t)(lo >> 5) * 8192 + w * 2048;
#pragma unroll
    for (int j = 0; j < 4; j++) {
      GLDS16(ks + j * 512 + lane * 8, &kt[0][w * 2048 + j * 512]);
      GLDS16(vs + j * 512 + lane * 8, &vt[0][w * 2048 + j * 512]);
    }
  }
  __syncthreads();

  int cur = 0;
  for (int key0 = lo; key0 < hiend; key0 += 32) {
    // prefetch next tile into the other buffer
    if (key0 + 32 < hiend) {
      const unsigned short* ks = kslabs + (size_t)((key0 + 32) >> 5) * 8192 + w * 2048;
      const unsigned short* vs = vslabs + (size_t)((key0 + 32) >> 5) * 8192 + w * 2048;
#pragma unroll
      for (int j = 0; j < 4; j++) {
        GLDS16(ks + j * 512 + lane * 8, &kt[cur ^ 1][w * 2048 + j * 512]);
        GLDS16(vs + j * 512 + lane * 8, &vt[cur ^ 1][w * 2048 + j * 512]);
      }
    }
    const unsigned short* kc = kt[cur];
    const unsigned short* vc = vt[cur];

    f32x4 st0 = (f32x4){0.f, 0.f, 0.f, 0.f}, st1 = (f32x4){0.f, 0.f, 0.f, 0.f};
#pragma unroll
    for (int c = 0; c < 8; c++) {  // S^T = K . Q^T over HD, swizzled LDS reads
      int x0 = (((c * 4 + g) ^ (r & 7)) << 3);
      bf16x8 kf0 = *(const bf16x8*)(kc + r * 256 + x0);
      bf16x8 kf1 = *(const bf16x8*)(kc + (16 + r) * 256 + x0);
      st0 = __builtin_amdgcn_mfma_f32_16x16x32_bf16(kf0, qf[c], st0, 0, 0, 0);
      st1 = __builtin_amdgcn_mfma_f32_16x16x32_bf16(kf1, qf[c], st1, 0, 0, 0);
    }
    float p[2][4];
    float pm = -3e30f;
#pragma unroll
    for (int t = 0; t < 2; t++)
#pragma unroll
      for (int e = 0; e < 4; e++) {
        int key = key0 + t * 16 + 4 * g + e;
        float sv = (t == 0 ? st0[e] : st1[e]) * sc2;
        sv = (key <= qi && key > qi - 1024) ? sv : -2e30f;  // window mask
        p[t][e] = sv;
        pm = fmaxf(pm, sv);
      }
    pm = fmaxf(pm, __shfl_xor(pm, 16));
    pm = fmaxf(pm, __shfl_xor(pm, 32));
    float newm = fmaxf(m, pm);
    float f = exp2f(m - newm);
    m = newm;
    float ps = 0.0f;
#pragma unroll
    for (int t = 0; t < 2; t++)
#pragma unroll
      for (int e = 0; e < 4; e++) {
        float pe = exp2f(p[t][e] - m);
        p[t][e] = pe;
        ps += pe;
      }
    ps += __shfl_xor(ps, 16);
    ps += __shfl_xor(ps, 32);
    lsum = lsum * f + ps;
#pragma unroll
    for (int i = 0; i < 16; i++) {
      o[i][0] *= f; o[i][1] *= f; o[i][2] *= f; o[i][3] *= f;
    }
    // build P^T B-fragment: lane needs P^T[key0+8g+e2][qrow r]
    short pk[8];
#pragma unroll
    for (int e2 = 0; e2 < 8; e2++) {
      int srcl = r + 16 * (2 * (g & 1) + (e2 >> 2));
      float a0 = __shfl(p[0][e2 & 3], srcl);
      float a1 = __shfl(p[1][e2 & 3], srcl);
      pk[e2] = (short)f2bf((g < 2) ? a0 : a1);
    }
    bf16x8 pf = {pk[0], pk[1], pk[2], pk[3], pk[4], pk[5], pk[6], pk[7]};
    int yx = ((g ^ ((r >> 1) & 3)) << 3);
#pragma unroll
    for (int c2 = 0; c2 < 16; c2++) {  // O^T += V^T . P^T, swizzled LDS reads
      bf16x8 vf = *(const bf16x8*)(vc + (c2 * 16 + r) * 32 + yx);
      o[c2] = __builtin_amdgcn_mfma_f32_16x16x32_bf16(vf, pf, o[c2], 0, 0, 0);
    }
    __syncthreads();
    cur ^= 1;
  }
  float linv = 1.0f / lsum;
  unsigned short* arow = attn + ((size_t)(b * S_LEN) + q0 + w * 16 + r) * (HQ_N * HD_N) + h * HD_N;
#pragma unroll
  for (int c2 = 0; c2 < 16; c2++) {
    unsigned int w0 = (unsigned)f2bf(o[c2][0] * linv) | ((unsigned)f2bf(o[c2][1] * linv) << 16);
    unsigned int w1 = (unsigned)f2bf(o[c2][2] * linv) | ((unsigned)f2bf(o[c2][3] * linv) << 16);
    *(unsigned int*)(arow + c2 * 16 + 4 * g) = w0;
    *(unsigned int*)(arow + c2 * 16 + 4 * g + 2) = w1;
  }
}

extern "C" void kernel_launch(void* const* d_in, const int* in_sizes, int n_in,
                              void* d_out, int out_size, void* d_ws, size_t ws_size,
                              hipStream_t stream) {
  const float* hid  = (const float*)d_in[0];
  const float* cosb = (const float*)d_in[1];
  const float* sinb = (const float*)d_in[2];
  const float* Wq   = (const float*)d_in[4];
  const float* Wk   = (const float*)d_in[5];
  const float* Wv   = (const float*)d_in[6];
  const float* Wo   = (const float*)d_in[7];
  const float* qw   = (const float*)d_in[8];
  const float* kw   = (const float*)d_in[9];

  char* ws = (char*)d_ws;
  unsigned short* Xbf   = (unsigned short*)(ws + 0);            // 4096x2560 bf16
  unsigned short* Wcat  = (unsigned short*)(ws + 20971520);     // 4096x2560 bf16
  unsigned short* Wob   = (unsigned short*)(ws + 41943040);     // 2560x2048 bf16
  unsigned short* QKV   = (unsigned short*)(ws + 52428800);     // 4096x4096 bf16
  unsigned short* qbuf  = (unsigned short*)(ws + 85983232);     // 2*8*2048*256
  unsigned short* kbuf  = (unsigned short*)(ws + 102760448);    // 2*4*2048*256 (tiled)
  unsigned short* vbuf  = (unsigned short*)(ws + 111149056);    // 2*4*2048*256 (tiled)
  unsigned short* attnb = (unsigned short*)(ws + 119537664);    // 4096x2048 bf16
  // total: 136,314,880 B

  // 1) casts
  cvt_kernel<<<10240, 256, 0, stream>>>(hid, Xbf, 2621440);
  cvt_kernel<<<5120, 256, 0, stream>>>(Wq, Wcat, 1310720);
  cvt_kernel<<<2560, 256, 0, stream>>>(Wk, Wcat + 5242880, 655360);
  cvt_kernel<<<2560, 256, 0, stream>>>(Wv, Wcat + 7864320, 655360);
  cvt_kernel<<<5120, 256, 0, stream>>>(Wo, Wob, 1310720);
  // 2) fused QKV projection: QKV = X @ Wcat^T
  gemm_lds<1><<<dim3(32, 32), 256, 0, stream>>>(Xbf, Wcat, QKV, 4096, 4096, 2560);
  // 3) RMSNorm + RoPE (K/V written tiled+swizzled for attn LDS staging)
  rms_rope_kernel<<<16384, 256, 0, stream>>>(QKV, cosb, sinb, qw, kw, qbuf, kbuf, vbuf);
  // 4) sliding-window flash attention
  attn_kernel<<<512, 256, 0, stream>>>(qbuf, kbuf, vbuf, attnb);
  // 5) output projection: d_out = attn @ Wo^T (fp32 out)
  gemm_lds<0><<<dim3(20, 32), 256, 0, stream>>>(attnb, Wob, (float*)d_out, 4096, 2560, 2048);
}

// Round 4
// 334.658 us; speedup vs baseline: 2.4347x; 1.1954x over previous
//
#include <hip/hip_runtime.h>

#define S_LEN 2048
#define HIDN  2560
#define HQ_N  8
#define HKV_N 4
#define HD_N  256
#define NQKV  4096   // HQ*HD + 2*HKV*HD
#define MROWS 4096   // B*S

typedef __attribute__((ext_vector_type(8))) short bf16x8;
typedef __attribute__((ext_vector_type(4))) float f32x4;
typedef __attribute__((ext_vector_type(4))) unsigned short u16x4;

typedef const __attribute__((address_space(1))) unsigned int* gas_t;
typedef __attribute__((address_space(3))) unsigned int* las_t;
#define GLDS16(gp, lp) __builtin_amdgcn_global_load_lds((gas_t)(const void*)(gp), \
                                                        (las_t)(void*)(lp), 16, 0, 0)

static __device__ __forceinline__ float bf2f(unsigned short u) {
  unsigned int x = ((unsigned int)u) << 16;
  return __builtin_bit_cast(float, x);
}
static __device__ __forceinline__ unsigned short f2bf(float f) {
  unsigned int u = __builtin_bit_cast(unsigned int, f);
  u += 0x7fffu + ((u >> 16) & 1u);
  return (unsigned short)(u >> 16);
}

// ---------------- fp32 -> bf16 cast (vectorized x4) ----------------
__global__ void cvt_kernel(const float* __restrict__ src,
                           unsigned short* __restrict__ dst, int n4) {
  int i = blockIdx.x * 256 + threadIdx.x;
  if (i >= n4) return;
  f32x4 v = ((const f32x4*)src)[i];
  u16x4 o;
  o[0] = f2bf(v[0]); o[1] = f2bf(v[1]); o[2] = f2bf(v[2]); o[3] = f2bf(v[3]);
  ((u16x4*)dst)[i] = o;
}

// ---------------- 256x256-tile pipelined GEMM: C[m][n] = sum_k A[m][k]*B[n][k] ----------
// 512 thr = 8 waves (2M x 4N), wave tile 128x64. BK=32, ring-of-3 LDS K-tile buffers
// (96 KB). Counted vmcnt(4) per K-tile; 2 phases/K-tile of 16 MFMA between raw barriers.
// LDS swizzle: physical 16B-slot = logical ^ ((row>>1)&3)  (2-way banks only = free).
// GLDS dest stays linear; global SOURCE is inverse-swizzled (rule #21).
template <int OUT_BF16>
__global__ __launch_bounds__(512, 2) void gemm8p(const unsigned short* __restrict__ A,
                                                 const unsigned short* __restrict__ B,
                                                 void* __restrict__ C,
                                                 int M, int N, int K, int gx) {
  __shared__ unsigned short lds[49152];  // 3 bufs x (A 8192 + B 8192 elems)
  const int tid = threadIdx.x;
  const int lane = tid & 63;
  const int w = tid >> 6;
  const int r = lane & 15, g = lane >> 4;
  const int wr = w >> 2, wc = w & 3;
  const int NT = K >> 5;

  // XCD-aware bijective block swizzle (grid sizes are multiples of 8)
  const int nwg = gridDim.x;
  const int cpx = nwg >> 3;
  const int bid = blockIdx.x;
  const int sbid = (bid & 7) * cpx + (bid >> 3);
  const int bx = sbid % gx, by = sbid / gx;
  const int brow = by * 256, bcol = bx * 256;

  // staging: thread t covers physical (row = t>>2 [+128], slot = t&3); global source
  // column slot is inverse-swizzled: (t&3) ^ ((t>>3)&3)
  const int srow = tid >> 2;
  const int sw8 = ((tid & 3) ^ ((tid >> 3) & 3)) * 8;
  const unsigned short* gA0 = A + (size_t)(brow + srow) * K + sw8;
  const unsigned short* gA1 = A + (size_t)(brow + 128 + srow) * K + sw8;
  const unsigned short* gB0 = B + (size_t)(bcol + srow) * K + sw8;
  const unsigned short* gB1 = B + (size_t)(bcol + 128 + srow) * K + sw8;
  // per-wave linear LDS staging bases (element offsets within a buf)
  const int sdA0 = w * 512;
  const int sdA1 = 4096 + w * 512;
  const int sdB0 = 8192 + w * 512;
  const int sdB1 = 12288 + w * 512;

  // swizzled ds_read offsets
  const int swz = (g ^ ((r >> 1) & 3)) * 8;
  int aoffs[2][4], boffs[4];
#pragma unroll
  for (int mf = 0; mf < 4; mf++) {
    aoffs[0][mf] = (wr * 128 + mf * 16 + r) * 32 + swz;
    aoffs[1][mf] = (wr * 128 + 64 + mf * 16 + r) * 32 + swz;
    boffs[mf] = 8192 + (wc * 64 + mf * 16 + r) * 32 + swz;
  }

  f32x4 acc[8][4];
#pragma unroll
  for (int i = 0; i < 8; i++)
#pragma unroll
    for (int j = 0; j < 4; j++) acc[i][j] = (f32x4){0.f, 0.f, 0.f, 0.f};

  // prologue: stage K-tiles 0 and 1; leave tile 1 in flight (invariant: 4 outstanding)
  {
    unsigned short* b0 = lds;
    GLDS16(gA0, b0 + sdA0); GLDS16(gA1, b0 + sdA1);
    GLDS16(gB0, b0 + sdB0); GLDS16(gB1, b0 + sdB1);
    unsigned short* b1 = lds + 16384;
    GLDS16(gA0 + 32, b1 + sdA0); GLDS16(gA1 + 32, b1 + sdA1);
    GLDS16(gB0 + 32, b1 + sdB0); GLDS16(gB1 + 32, b1 + sdB1);
  }
  asm volatile("s_waitcnt vmcnt(4)" ::: "memory");
  __builtin_amdgcn_sched_barrier(0);
  __builtin_amdgcn_s_barrier();

  int o_c = 0, o_n = 16384, o_s = 32768;
  for (int t = 0; t < NT; ++t) {
    const unsigned short* cb = lds + o_c;
    unsigned short* sb = lds + o_s;
    const int kst = (t + 2) << 5;
    const bool st = (t + 2) < NT;

    // ---------- phase A (mh=0): read A-half0 + all B; stage next A ----------
    bf16x8 a0[4], bb[4];
#pragma unroll
    for (int mf = 0; mf < 4; mf++) a0[mf] = *(const bf16x8*)(cb + aoffs[0][mf]);
#pragma unroll
    for (int nf = 0; nf < 4; nf++) bb[nf] = *(const bf16x8*)(cb + boffs[nf]);
    if (st) { GLDS16(gA0 + kst, sb + sdA0); GLDS16(gA1 + kst, sb + sdA1); }
    __builtin_amdgcn_sched_barrier(0);
    __builtin_amdgcn_s_barrier();
    asm volatile("s_waitcnt lgkmcnt(0)" ::: "memory");
    __builtin_amdgcn_sched_barrier(0);
    __builtin_amdgcn_s_setprio(1);
#pragma unroll
    for (int mf = 0; mf < 4; mf++)
#pragma unroll
      for (int nf = 0; nf < 4; nf++)
        acc[mf][nf] = __builtin_amdgcn_mfma_f32_16x16x32_bf16(a0[mf], bb[nf], acc[mf][nf], 0, 0, 0);
    __builtin_amdgcn_s_setprio(0);
    __builtin_amdgcn_sched_barrier(0);
    __builtin_amdgcn_s_barrier();

    // ---------- phase B (mh=1): read A-half1; stage next B; counted vmcnt ----------
    bf16x8 a1[4];
#pragma unroll
    for (int mf = 0; mf < 4; mf++) a1[mf] = *(const bf16x8*)(cb + aoffs[1][mf]);
    if (st) {
      GLDS16(gB0 + kst, sb + sdB0); GLDS16(gB1 + kst, sb + sdB1);
      asm volatile("s_waitcnt vmcnt(4)" ::: "memory");
    } else {
      asm volatile("s_waitcnt vmcnt(0)" ::: "memory");
    }
    __builtin_amdgcn_sched_barrier(0);
    __builtin_amdgcn_s_barrier();
    asm volatile("s_waitcnt lgkmcnt(0)" ::: "memory");
    __builtin_amdgcn_sched_barrier(0);
    __builtin_amdgcn_s_setprio(1);
#pragma unroll
    for (int mf = 0; mf < 4; mf++)
#pragma unroll
      for (int nf = 0; nf < 4; nf++)
        acc[4 + mf][nf] = __builtin_amdgcn_mfma_f32_16x16x32_bf16(a1[mf], bb[nf], acc[4 + mf][nf], 0, 0, 0);
    __builtin_amdgcn_s_setprio(0);
    __builtin_amdgcn_sched_barrier(0);
    __builtin_amdgcn_s_barrier();

    int tmp = o_c; o_c = o_n; o_n = o_s; o_s = tmp;
  }

  // epilogue: acc[mh*4+mf][nf] -> C[brow + wr*128 + mh*64 + mf*16 + g*4 + e][bcol + wc*64 + nf*16 + r]
#pragma unroll
  for (int i = 0; i < 8; i++)
#pragma unroll
    for (int j = 0; j < 4; j++) {
      const int col = bcol + wc * 64 + j * 16 + r;
      const int rowb = brow + wr * 128 + (i >> 2) * 64 + (i & 3) * 16 + g * 4;
#pragma unroll
      for (int e = 0; e < 4; e++) {
        if (OUT_BF16)
          ((unsigned short*)C)[(size_t)(rowb + e) * N + col] = f2bf(acc[i][j][e]);
        else
          ((float*)C)[(size_t)(rowb + e) * N + col] = acc[i][j][e];
      }
    }
}

// ---------------- fused RMSNorm (+weight) + RoPE ----------------
// q: [b][h][s][d] row-major bf16.
// k: per-32-key tiled slabs, slot pre-swizzled: slot' = (d>>3) ^ (kr&7)
// v: per-32-key tiled slabs, slot pre-swizzled: slot' = (ks>>3) ^ ((d>>1)&3)
__global__ __launch_bounds__(256) void rms_rope_kernel(
    const unsigned short* __restrict__ qkv, const float* __restrict__ cosb,
    const float* __restrict__ sinb, const float* __restrict__ qw,
    const float* __restrict__ kw, unsigned short* __restrict__ qo,
    unsigned short* __restrict__ ko, unsigned short* __restrict__ vo) {
  int wid = (blockIdx.x * 256 + threadIdx.x) >> 6;
  int lane = threadIdx.x & 63;
  int row = wid >> 4;   // 0..4095 (= b*2048 + s)
  int unit = wid & 15;  // 0..7 q heads, 8..11 k heads, 12..15 v heads
  int b = row >> 11, s = row & 2047;
  int d0 = lane * 4;
  const unsigned short* x = qkv + (size_t)row * NQKV + unit * HD_N + d0;
  u16x4 xb = *(const u16x4*)x;
  float v[4];
#pragma unroll
  for (int j = 0; j < 4; j++) v[j] = bf2f(xb[j]);
  float ss = v[0] * v[0] + v[1] * v[1] + v[2] * v[2] + v[3] * v[3];
#pragma unroll
  for (int off = 32; off >= 1; off >>= 1) ss += __shfl_xor(ss, off);
  float inv = 1.0f / sqrtf(ss * (1.0f / 256.0f) + 1e-6f);

  int kb = s >> 5;
  if (unit >= 12) {  // v: norm only, tiled+swizzled
    int hv = unit - 12;
    int ks = s & 31;
    unsigned short* slab = vo + ((size_t)(b * HKV_N + hv) * 64 + kb) * 8192;
#pragma unroll
    for (int j = 0; j < 4; j++) {
      int d = d0 + j;
      int pos = d * 32 + (((ks >> 3) ^ ((d >> 1) & 3)) << 3) + (ks & 7);
      slab[pos] = f2bf(v[j] * inv);
    }
    return;
  }
  const float* wv = (unit < 8) ? qw : kw;
  f32x4 wl = *(const f32x4*)(wv + d0);
  float y[4];
#pragma unroll
  for (int j = 0; j < 4; j++) y[j] = v[j] * inv * wl[j];
  float yp[4];
#pragma unroll
  for (int j = 0; j < 4; j++) yp[j] = __shfl_xor(y[j], 32);  // element at d ^ 128
  f32x4 cv = *(const f32x4*)(cosb + (size_t)row * HD_N + d0);
  f32x4 sv = *(const f32x4*)(sinb + (size_t)row * HD_N + d0);
  u16x4 out;
#pragma unroll
  for (int j = 0; j < 4; j++) {
    float rot = (d0 < 128) ? -yp[j] : yp[j];
    out[j] = f2bf(y[j] * cv[j] + rot * sv[j]);
  }
  if (unit < 8) {
    unsigned short* dst = qo + ((size_t)(b * HQ_N + unit) * S_LEN + s) * HD_N + d0;
    *(u16x4*)dst = out;
  } else {
    int kv = unit - 8;
    int kr = s & 31;
    unsigned short* dst = ko + ((size_t)(b * HKV_N + kv) * 64 + kb) * 8192 + kr * 256 +
                          (((d0 >> 3) ^ (kr & 7)) << 3) + (d0 & 7);
    *(u16x4*)dst = out;
  }
}

// ---------------- flash attention: 4 waves/block, QBLK=64, K/V LDS double-buffered ------
__global__ __launch_bounds__(256) void attn_kernel(const unsigned short* __restrict__ qb,
                                                   const unsigned short* __restrict__ kb_,
                                                   const unsigned short* __restrict__ vb_,
                                                   unsigned short* __restrict__ attn) {
  __shared__ unsigned short kt[2][8192];
  __shared__ unsigned short vt[2][8192];
  const int lane = threadIdx.x & 63;
  const int w = threadIdx.x >> 6;
  const int r = lane & 15, g = lane >> 4;
  const int blk = blockIdx.x;
  const int qt = blk & 31;
  const int h = (blk >> 5) & 7;
  const int b = blk >> 8;
  const int kvh = h >> 1;
  const int q0 = qt * 64;
  const int qi = q0 + w * 16 + r;  // this lane's q-row
  const unsigned short* qbase = qb + ((size_t)(b * HQ_N + h) * S_LEN + q0 + w * 16) * HD_N;
  const unsigned short* kslabs = kb_ + (size_t)(b * HKV_N + kvh) * S_LEN * HD_N;
  const unsigned short* vslabs = vb_ + (size_t)(b * HKV_N + kvh) * S_LEN * HD_N;

  bf16x8 qf[8];
#pragma unroll
  for (int c = 0; c < 8; c++)
    qf[c] = *(const bf16x8*)(qbase + (size_t)r * HD_N + c * 32 + g * 8);

  f32x4 o[16];
#pragma unroll
  for (int i = 0; i < 16; i++) o[i] = (f32x4){0.f, 0.f, 0.f, 0.f};
  float m = -1e30f, lsum = 0.0f;
  const float sc2 = 0.0625f * 1.4426950408889634f;  // HD^-0.5 * log2(e)

  int lo = q0 - 1023; if (lo < 0) lo = 0; lo &= ~31;
  const int hiend = q0 + 64;

  // prologue stage
  {
    const unsigned short* ks = kslabs + (size_t)(lo >> 5) * 8192 + w * 2048;
    const unsigned short* vs = vslabs + (size_t)(lo >> 5) * 8192 + w * 2048;
#pragma unroll
    for (int j = 0; j < 4; j++) {
      GLDS16(ks + j * 512 + lane * 8, &kt[0][w * 2048 + j * 512]);
      GLDS16(vs + j * 512 + lane * 8, &vt[0][w * 2048 + j * 512]);
    }
  }
  __syncthreads();

  int cur = 0;
  for (int key0 = lo; key0 < hiend; key0 += 32) {
    if (key0 + 32 < hiend) {
      const unsigned short* ks = kslabs + (size_t)((key0 + 32) >> 5) * 8192 + w * 2048;
      const unsigned short* vs = vslabs + (size_t)((key0 + 32) >> 5) * 8192 + w * 2048;
#pragma unroll
      for (int j = 0; j < 4; j++) {
        GLDS16(ks + j * 512 + lane * 8, &kt[cur ^ 1][w * 2048 + j * 512]);
        GLDS16(vs + j * 512 + lane * 8, &vt[cur ^ 1][w * 2048 + j * 512]);
      }
    }
    const unsigned short* kc = kt[cur];
    const unsigned short* vc = vt[cur];

    f32x4 st0 = (f32x4){0.f, 0.f, 0.f, 0.f}, st1 = (f32x4){0.f, 0.f, 0.f, 0.f};
#pragma unroll
    for (int c = 0; c < 8; c++) {  // S^T = K . Q^T over HD, swizzled LDS reads
      int x0 = (((c * 4 + g) ^ (r & 7)) << 3);
      bf16x8 kf0 = *(const bf16x8*)(kc + r * 256 + x0);
      bf16x8 kf1 = *(const bf16x8*)(kc + (16 + r) * 256 + x0);
      st0 = __builtin_amdgcn_mfma_f32_16x16x32_bf16(kf0, qf[c], st0, 0, 0, 0);
      st1 = __builtin_amdgcn_mfma_f32_16x16x32_bf16(kf1, qf[c], st1, 0, 0, 0);
    }
    float p[2][4];
    float pm = -3e30f;
#pragma unroll
    for (int t = 0; t < 2; t++)
#pragma unroll
      for (int e = 0; e < 4; e++) {
        int key = key0 + t * 16 + 4 * g + e;
        float sv = (t == 0 ? st0[e] : st1[e]) * sc2;
        sv = (key <= qi && key > qi - 1024) ? sv : -2e30f;  // window mask
        p[t][e] = sv;
        pm = fmaxf(pm, sv);
      }
    pm = fmaxf(pm, __shfl_xor(pm, 16));
    pm = fmaxf(pm, __shfl_xor(pm, 32));
    float newm = fmaxf(m, pm);
    float f = exp2f(m - newm);
    m = newm;
    float ps = 0.0f;
#pragma unroll
    for (int t = 0; t < 2; t++)
#pragma unroll
      for (int e = 0; e < 4; e++) {
        float pe = exp2f(p[t][e] - m);
        p[t][e] = pe;
        ps += pe;
      }
    ps += __shfl_xor(ps, 16);
    ps += __shfl_xor(ps, 32);
    lsum = lsum * f + ps;
#pragma unroll
    for (int i = 0; i < 16; i++) {
      o[i][0] *= f; o[i][1] *= f; o[i][2] *= f; o[i][3] *= f;
    }
    short pk[8];
#pragma unroll
    for (int e2 = 0; e2 < 8; e2++) {
      int srcl = r + 16 * (2 * (g & 1) + (e2 >> 2));
      float a0 = __shfl(p[0][e2 & 3], srcl);
      float a1 = __shfl(p[1][e2 & 3], srcl);
      pk[e2] = (short)f2bf((g < 2) ? a0 : a1);
    }
    bf16x8 pf = {pk[0], pk[1], pk[2], pk[3], pk[4], pk[5], pk[6], pk[7]};
    int yx = ((g ^ ((r >> 1) & 3)) << 3);
#pragma unroll
    for (int c2 = 0; c2 < 16; c2++) {  // O^T += V^T . P^T, swizzled LDS reads
      bf16x8 vf = *(const bf16x8*)(vc + (c2 * 16 + r) * 32 + yx);
      o[c2] = __builtin_amdgcn_mfma_f32_16x16x32_bf16(vf, pf, o[c2], 0, 0, 0);
    }
    __syncthreads();
    cur ^= 1;
  }
  float linv = 1.0f / lsum;
  unsigned short* arow = attn + ((size_t)(b * S_LEN) + q0 + w * 16 + r) * (HQ_N * HD_N) + h * HD_N;
#pragma unroll
  for (int c2 = 0; c2 < 16; c2++) {
    unsigned int w0 = (unsigned)f2bf(o[c2][0] * linv) | ((unsigned)f2bf(o[c2][1] * linv) << 16);
    unsigned int w1 = (unsigned)f2bf(o[c2][2] * linv) | ((unsigned)f2bf(o[c2][3] * linv) << 16);
    *(unsigned int*)(arow + c2 * 16 + 4 * g) = w0;
    *(unsigned int*)(arow + c2 * 16 + 4 * g + 2) = w1;
  }
}

extern "C" void kernel_launch(void* const* d_in, const int* in_sizes, int n_in,
                              void* d_out, int out_size, void* d_ws, size_t ws_size,
                              hipStream_t stream) {
  const float* hid  = (const float*)d_in[0];
  const float* cosb = (const float*)d_in[1];
  const float* sinb = (const float*)d_in[2];
  const float* Wq   = (const float*)d_in[4];
  const float* Wk   = (const float*)d_in[5];
  const float* Wv   = (const float*)d_in[6];
  const float* Wo   = (const float*)d_in[7];
  const float* qw   = (const float*)d_in[8];
  const float* kw   = (const float*)d_in[9];

  char* ws = (char*)d_ws;
  unsigned short* Xbf   = (unsigned short*)(ws + 0);            // 4096x2560 bf16
  unsigned short* Wcat  = (unsigned short*)(ws + 20971520);     // 4096x2560 bf16
  unsigned short* Wob   = (unsigned short*)(ws + 41943040);     // 2560x2048 bf16
  unsigned short* QKV   = (unsigned short*)(ws + 52428800);     // 4096x4096 bf16
  unsigned short* qbuf  = (unsigned short*)(ws + 85983232);     // 2*8*2048*256
  unsigned short* kbuf  = (unsigned short*)(ws + 102760448);    // 2*4*2048*256 (tiled)
  unsigned short* vbuf  = (unsigned short*)(ws + 111149056);    // 2*4*2048*256 (tiled)
  unsigned short* attnb = (unsigned short*)(ws + 119537664);    // 4096x2048 bf16
  // total: 136,314,880 B

  // 1) casts
  cvt_kernel<<<10240, 256, 0, stream>>>(hid, Xbf, 2621440);
  cvt_kernel<<<5120, 256, 0, stream>>>(Wq, Wcat, 1310720);
  cvt_kernel<<<2560, 256, 0, stream>>>(Wk, Wcat + 5242880, 655360);
  cvt_kernel<<<2560, 256, 0, stream>>>(Wv, Wcat + 7864320, 655360);
  cvt_kernel<<<5120, 256, 0, stream>>>(Wo, Wob, 1310720);
  // 2) fused QKV projection: QKV = X @ Wcat^T  (grid 16x16 = 256 blocks)
  gemm8p<1><<<256, 512, 0, stream>>>(Xbf, Wcat, QKV, 4096, 4096, 2560, 16);
  // 3) RMSNorm + RoPE (K/V written tiled+swizzled for attn LDS staging)
  rms_rope_kernel<<<16384, 256, 0, stream>>>(QKV, cosb, sinb, qw, kw, qbuf, kbuf, vbuf);
  // 4) sliding-window flash attention
  attn_kernel<<<512, 256, 0, stream>>>(qbuf, kbuf, vbuf, attnb);
  // 5) output projection: d_out = attn @ Wo^T (fp32 out, grid 10x16 = 160 blocks)
  gemm8p<0><<<160, 512, 0, stream>>>(attnb, Wob, (float*)d_out, 4096, 2560, 2048, 10);
}

// Round 5
// 321.669 us; speedup vs baseline: 2.5330x; 1.0404x over previous
//
#include <hip/hip_runtime.h>

#define S_LEN 2048
#define HIDN  2560
#define HQ_N  8
#define HKV_N 4
#define HD_N  256
#define NQKV  4096   // HQ*HD + 2*HKV*HD
#define MROWS 4096   // B*S
#define SC2   0.09016844005556021f  // HD^-0.5 * log2(e), folded into Q at producer

typedef __attribute__((ext_vector_type(8))) short bf16x8;
typedef __attribute__((ext_vector_type(4))) float f32x4;
typedef __attribute__((ext_vector_type(4))) unsigned short u16x4;

typedef const __attribute__((address_space(1))) unsigned int* gas_t;
typedef __attribute__((address_space(3))) unsigned int* las_t;
#define GLDS16(gp, lp) __builtin_amdgcn_global_load_lds((gas_t)(const void*)(gp), \
                                                        (las_t)(void*)(lp), 16, 0, 0)

static __device__ __forceinline__ float bf2f(unsigned short u) {
  unsigned int x = ((unsigned int)u) << 16;
  return __builtin_bit_cast(float, x);
}
static __device__ __forceinline__ unsigned short f2bf(float f) {
  unsigned int u = __builtin_bit_cast(unsigned int, f);
  u += 0x7fffu + ((u >> 16) & 1u);
  return (unsigned short)(u >> 16);
}

// ---------------- fp32 -> bf16 cast (vectorized x4) ----------------
__global__ void cvt_kernel(const float* __restrict__ src,
                           unsigned short* __restrict__ dst, int n4) {
  int i = blockIdx.x * 256 + threadIdx.x;
  if (i >= n4) return;
  f32x4 v = ((const f32x4*)src)[i];
  u16x4 o;
  o[0] = f2bf(v[0]); o[1] = f2bf(v[1]); o[2] = f2bf(v[2]); o[3] = f2bf(v[3]);
  ((u16x4*)dst)[i] = o;
}

// ---------------- 256x256-tile pipelined GEMM: C[m][n] = sum_k A[m][k]*B[n][k] ----------
// 512 thr = 8 waves (2M x 4N), wave tile 128x64. BK=32, ring-of-3 LDS K-tile buffers
// (96 KB). Counted vmcnt(4) per K-tile; 2 phases/K-tile of 16 MFMA between raw barriers.
template <int OUT_BF16>
__global__ __launch_bounds__(512, 2) void gemm8p(const unsigned short* __restrict__ A,
                                                 const unsigned short* __restrict__ B,
                                                 void* __restrict__ C,
                                                 int M, int N, int K, int gx) {
  __shared__ unsigned short lds[49152];  // 3 bufs x (A 8192 + B 8192 elems)
  const int tid = threadIdx.x;
  const int lane = tid & 63;
  const int w = tid >> 6;
  const int r = lane & 15, g = lane >> 4;
  const int wr = w >> 2, wc = w & 3;
  const int NT = K >> 5;

  const int nwg = gridDim.x;
  const int cpx = nwg >> 3;
  const int bid = blockIdx.x;
  const int sbid = (bid & 7) * cpx + (bid >> 3);
  const int bx = sbid % gx, by = sbid / gx;
  const int brow = by * 256, bcol = bx * 256;

  const int srow = tid >> 2;
  const int sw8 = ((tid & 3) ^ ((tid >> 3) & 3)) * 8;
  const unsigned short* gA0 = A + (size_t)(brow + srow) * K + sw8;
  const unsigned short* gA1 = A + (size_t)(brow + 128 + srow) * K + sw8;
  const unsigned short* gB0 = B + (size_t)(bcol + srow) * K + sw8;
  const unsigned short* gB1 = B + (size_t)(bcol + 128 + srow) * K + sw8;
  const int sdA0 = w * 512;
  const int sdA1 = 4096 + w * 512;
  const int sdB0 = 8192 + w * 512;
  const int sdB1 = 12288 + w * 512;

  const int swz = (g ^ ((r >> 1) & 3)) * 8;
  int aoffs[2][4], boffs[4];
#pragma unroll
  for (int mf = 0; mf < 4; mf++) {
    aoffs[0][mf] = (wr * 128 + mf * 16 + r) * 32 + swz;
    aoffs[1][mf] = (wr * 128 + 64 + mf * 16 + r) * 32 + swz;
    boffs[mf] = 8192 + (wc * 64 + mf * 16 + r) * 32 + swz;
  }

  f32x4 acc[8][4];
#pragma unroll
  for (int i = 0; i < 8; i++)
#pragma unroll
    for (int j = 0; j < 4; j++) acc[i][j] = (f32x4){0.f, 0.f, 0.f, 0.f};

  {
    unsigned short* b0 = lds;
    GLDS16(gA0, b0 + sdA0); GLDS16(gA1, b0 + sdA1);
    GLDS16(gB0, b0 + sdB0); GLDS16(gB1, b0 + sdB1);
    unsigned short* b1 = lds + 16384;
    GLDS16(gA0 + 32, b1 + sdA0); GLDS16(gA1 + 32, b1 + sdA1);
    GLDS16(gB0 + 32, b1 + sdB0); GLDS16(gB1 + 32, b1 + sdB1);
  }
  asm volatile("s_waitcnt vmcnt(4)" ::: "memory");
  __builtin_amdgcn_sched_barrier(0);
  __builtin_amdgcn_s_barrier();

  int o_c = 0, o_n = 16384, o_s = 32768;
  for (int t = 0; t < NT; ++t) {
    const unsigned short* cb = lds + o_c;
    unsigned short* sb = lds + o_s;
    const int kst = (t + 2) << 5;
    const bool st = (t + 2) < NT;

    bf16x8 a0[4], bb[4];
#pragma unroll
    for (int mf = 0; mf < 4; mf++) a0[mf] = *(const bf16x8*)(cb + aoffs[0][mf]);
#pragma unroll
    for (int nf = 0; nf < 4; nf++) bb[nf] = *(const bf16x8*)(cb + boffs[nf]);
    if (st) { GLDS16(gA0 + kst, sb + sdA0); GLDS16(gA1 + kst, sb + sdA1); }
    __builtin_amdgcn_sched_barrier(0);
    __builtin_amdgcn_s_barrier();
    asm volatile("s_waitcnt lgkmcnt(0)" ::: "memory");
    __builtin_amdgcn_sched_barrier(0);
    __builtin_amdgcn_s_setprio(1);
#pragma unroll
    for (int mf = 0; mf < 4; mf++)
#pragma unroll
      for (int nf = 0; nf < 4; nf++)
        acc[mf][nf] = __builtin_amdgcn_mfma_f32_16x16x32_bf16(a0[mf], bb[nf], acc[mf][nf], 0, 0, 0);
    __builtin_amdgcn_s_setprio(0);
    __builtin_amdgcn_sched_barrier(0);
    __builtin_amdgcn_s_barrier();

    bf16x8 a1[4];
#pragma unroll
    for (int mf = 0; mf < 4; mf++) a1[mf] = *(const bf16x8*)(cb + aoffs[1][mf]);
    if (st) {
      GLDS16(gB0 + kst, sb + sdB0); GLDS16(gB1 + kst, sb + sdB1);
      asm volatile("s_waitcnt vmcnt(4)" ::: "memory");
    } else {
      asm volatile("s_waitcnt vmcnt(0)" ::: "memory");
    }
    __builtin_amdgcn_sched_barrier(0);
    __builtin_amdgcn_s_barrier();
    asm volatile("s_waitcnt lgkmcnt(0)" ::: "memory");
    __builtin_amdgcn_sched_barrier(0);
    __builtin_amdgcn_s_setprio(1);
#pragma unroll
    for (int mf = 0; mf < 4; mf++)
#pragma unroll
      for (int nf = 0; nf < 4; nf++)
        acc[4 + mf][nf] = __builtin_amdgcn_mfma_f32_16x16x32_bf16(a1[mf], bb[nf], acc[4 + mf][nf], 0, 0, 0);
    __builtin_amdgcn_s_setprio(0);
    __builtin_amdgcn_sched_barrier(0);
    __builtin_amdgcn_s_barrier();

    int tmp = o_c; o_c = o_n; o_n = o_s; o_s = tmp;
  }

#pragma unroll
  for (int i = 0; i < 8; i++)
#pragma unroll
    for (int j = 0; j < 4; j++) {
      const int col = bcol + wc * 64 + j * 16 + r;
      const int rowb = brow + wr * 128 + (i >> 2) * 64 + (i & 3) * 16 + g * 4;
#pragma unroll
      for (int e = 0; e < 4; e++) {
        if (OUT_BF16)
          ((unsigned short*)C)[(size_t)(rowb + e) * N + col] = f2bf(acc[i][j][e]);
        else
          ((float*)C)[(size_t)(rowb + e) * N + col] = acc[i][j][e];
      }
    }
}

// ---------------- fused RMSNorm (+weight) + RoPE ----------------
// q: [b][h][s][d] row-major bf16, PRE-SCALED by SC2 (softmax scale folded in).
// k: per-32-key tiled slabs, slot pre-swizzled: slot' = (d>>3) ^ (kr&7)
// v: per-32-key tiled slabs, slot pre-swizzled: slot' = (ks>>3) ^ ((d>>1)&3)
__global__ __launch_bounds__(256) void rms_rope_kernel(
    const unsigned short* __restrict__ qkv, const float* __restrict__ cosb,
    const float* __restrict__ sinb, const float* __restrict__ qw,
    const float* __restrict__ kw, unsigned short* __restrict__ qo,
    unsigned short* __restrict__ ko, unsigned short* __restrict__ vo) {
  int wid = (blockIdx.x * 256 + threadIdx.x) >> 6;
  int lane = threadIdx.x & 63;
  int row = wid >> 4;   // 0..4095 (= b*2048 + s)
  int unit = wid & 15;  // 0..7 q heads, 8..11 k heads, 12..15 v heads
  int b = row >> 11, s = row & 2047;
  int d0 = lane * 4;
  const unsigned short* x = qkv + (size_t)row * NQKV + unit * HD_N + d0;
  u16x4 xb = *(const u16x4*)x;
  float v[4];
#pragma unroll
  for (int j = 0; j < 4; j++) v[j] = bf2f(xb[j]);
  float ss = v[0] * v[0] + v[1] * v[1] + v[2] * v[2] + v[3] * v[3];
#pragma unroll
  for (int off = 32; off >= 1; off >>= 1) ss += __shfl_xor(ss, off);
  float inv = 1.0f / sqrtf(ss * (1.0f / 256.0f) + 1e-6f);

  int kb = s >> 5;
  if (unit >= 12) {  // v: norm only, tiled+swizzled
    int hv = unit - 12;
    int ks = s & 31;
    unsigned short* slab = vo + ((size_t)(b * HKV_N + hv) * 64 + kb) * 8192;
#pragma unroll
    for (int j = 0; j < 4; j++) {
      int d = d0 + j;
      int pos = d * 32 + (((ks >> 3) ^ ((d >> 1) & 3)) << 3) + (ks & 7);
      slab[pos] = f2bf(v[j] * inv);
    }
    return;
  }
  const float* wv = (unit < 8) ? qw : kw;
  const float qsc = (unit < 8) ? SC2 : 1.0f;  // fold softmax scale into Q
  f32x4 wl = *(const f32x4*)(wv + d0);
  float y[4];
#pragma unroll
  for (int j = 0; j < 4; j++) y[j] = v[j] * inv * wl[j] * qsc;
  float yp[4];
#pragma unroll
  for (int j = 0; j < 4; j++) yp[j] = __shfl_xor(y[j], 32);  // element at d ^ 128
  f32x4 cv = *(const f32x4*)(cosb + (size_t)row * HD_N + d0);
  f32x4 sv = *(const f32x4*)(sinb + (size_t)row * HD_N + d0);
  u16x4 out;
#pragma unroll
  for (int j = 0; j < 4; j++) {
    float rot = (d0 < 128) ? -yp[j] : yp[j];
    out[j] = f2bf(y[j] * cv[j] + rot * sv[j]);
  }
  if (unit < 8) {
    unsigned short* dst = qo + ((size_t)(b * HQ_N + unit) * S_LEN + s) * HD_N + d0;
    *(u16x4*)dst = out;
  } else {
    int kv = unit - 8;
    int kr = s & 31;
    unsigned short* dst = ko + ((size_t)(b * HKV_N + kv) * 64 + kb) * 8192 + kr * 256 +
                          (((d0 >> 3) ^ (kr & 7)) << 3) + (d0 & 7);
    *(u16x4*)dst = out;
  }
}

// ---------------- flash attention: 4 waves/block, QBLK=64, K/V LDS double-buffered ------
// XCD-swizzled so each XCD's L2 serves one (b,kvh) K/V slab. Defer-max (THR=8) skips the
// O-rescale on most tiles. Waves skip compute on tiles outside their 16-row window.
__global__ __launch_bounds__(256) void attn_kernel(const unsigned short* __restrict__ qb,
                                                   const unsigned short* __restrict__ kb_,
                                                   const unsigned short* __restrict__ vb_,
                                                   unsigned short* __restrict__ attn) {
  __shared__ unsigned short kt[2][8192];
  __shared__ unsigned short vt[2][8192];
  const int lane = threadIdx.x & 63;
  const int w = threadIdx.x >> 6;
  const int r = lane & 15, g = lane >> 4;
  const int pblk = blockIdx.x;
  const int lb = (pblk & 7) * 64 + (pblk >> 3);  // XCD chunk = 64 blocks = one (b,kvh)
  const int qt = lb & 31;
  const int h = (lb >> 5) & 7;
  const int b = lb >> 8;
  const int kvh = h >> 1;
  const int q0 = qt * 64;
  const int qi = q0 + w * 16 + r;  // this lane's q-row
  const int wqmin = q0 + w * 16, wqmax = wqmin + 15;
  const unsigned short* qbase = qb + ((size_t)(b * HQ_N + h) * S_LEN + q0 + w * 16) * HD_N;
  const unsigned short* kslabs = kb_ + (size_t)(b * HKV_N + kvh) * S_LEN * HD_N;
  const unsigned short* vslabs = vb_ + (size_t)(b * HKV_N + kvh) * S_LEN * HD_N;

  bf16x8 qf[8];
#pragma unroll
  for (int c = 0; c < 8; c++)
    qf[c] = *(const bf16x8*)(qbase + (size_t)r * HD_N + c * 32 + g * 8);

  f32x4 o[16];
#pragma unroll
  for (int i = 0; i < 16; i++) o[i] = (f32x4){0.f, 0.f, 0.f, 0.f};
  float m = -1e30f, lsum = 0.0f;

  int lo = q0 - 1023; if (lo < 0) lo = 0; lo &= ~31;
  const int hiend = q0 + 64;

  // prologue stage
  {
    const unsigned short* ks = kslabs + (size_t)(lo >> 5) * 8192 + w * 2048;
    const unsigned short* vs = vslabs + (size_t)(lo >> 5) * 8192 + w * 2048;
#pragma unroll
    for (int j = 0; j < 4; j++) {
      GLDS16(ks + j * 512 + lane * 8, &kt[0][w * 2048 + j * 512]);
      GLDS16(vs + j * 512 + lane * 8, &vt[0][w * 2048 + j * 512]);
    }
  }
  __syncthreads();

  int cur = 0;
  for (int key0 = lo; key0 < hiend; key0 += 32) {
    if (key0 + 32 < hiend) {
      const unsigned short* ks = kslabs + (size_t)((key0 + 32) >> 5) * 8192 + w * 2048;
      const unsigned short* vs = vslabs + (size_t)((key0 + 32) >> 5) * 8192 + w * 2048;
#pragma unroll
      for (int j = 0; j < 4; j++) {
        GLDS16(ks + j * 512 + lane * 8, &kt[cur ^ 1][w * 2048 + j * 512]);
        GLDS16(vs + j * 512 + lane * 8, &vt[cur ^ 1][w * 2048 + j * 512]);
      }
    }
    // wave-level skip: tile outside this wave's 16-row window union
    if (key0 <= wqmax && key0 + 31 >= wqmin - 1023) {
      const unsigned short* kc = kt[cur];
      const unsigned short* vc = vt[cur];

      f32x4 st0 = (f32x4){0.f, 0.f, 0.f, 0.f}, st1 = (f32x4){0.f, 0.f, 0.f, 0.f};
      __builtin_amdgcn_s_setprio(1);
#pragma unroll
      for (int c = 0; c < 8; c++) {  // S^T = K . Q^T over HD, swizzled LDS reads
        int x0 = (((c * 4 + g) ^ (r & 7)) << 3);
        bf16x8 kf0 = *(const bf16x8*)(kc + r * 256 + x0);
        bf16x8 kf1 = *(const bf16x8*)(kc + (16 + r) * 256 + x0);
        st0 = __builtin_amdgcn_mfma_f32_16x16x32_bf16(kf0, qf[c], st0, 0, 0, 0);
        st1 = __builtin_amdgcn_mfma_f32_16x16x32_bf16(kf1, qf[c], st1, 0, 0, 0);
      }
      __builtin_amdgcn_s_setprio(0);
      float p[2][4];
      float pm = -3e30f;
#pragma unroll
      for (int t = 0; t < 2; t++)
#pragma unroll
        for (int e = 0; e < 4; e++) {
          int key = key0 + t * 16 + 4 * g + e;
          float sv = (t == 0 ? st0[e] : st1[e]);  // scale pre-folded into Q
          sv = (key <= qi && key > qi - 1024) ? sv : -2e30f;  // window mask
          p[t][e] = sv;
          pm = fmaxf(pm, sv);
        }
      pm = fmaxf(pm, __shfl_xor(pm, 16));
      pm = fmaxf(pm, __shfl_xor(pm, 32));
      // defer-max: skip O-rescale when max didn't grow by >8 (exp2 headroom 2^8)
      if (!__all(pm <= m + 8.0f)) {
        float newm = fmaxf(m, pm);
        float f = exp2f(m - newm);
        m = newm;
        lsum *= f;
#pragma unroll
        for (int i = 0; i < 16; i++) {
          o[i][0] *= f; o[i][1] *= f; o[i][2] *= f; o[i][3] *= f;
        }
      }
      float ps = 0.0f;
#pragma unroll
      for (int t = 0; t < 2; t++)
#pragma unroll
        for (int e = 0; e < 4; e++) {
          float pe = exp2f(p[t][e] - m);
          p[t][e] = pe;
          ps += pe;
        }
      ps += __shfl_xor(ps, 16);
      ps += __shfl_xor(ps, 32);
      lsum += ps;
      short pk[8];
#pragma unroll
      for (int e2 = 0; e2 < 8; e2++) {
        int srcl = r + 16 * (2 * (g & 1) + (e2 >> 2));
        float a0 = __shfl(p[0][e2 & 3], srcl);
        float a1 = __shfl(p[1][e2 & 3], srcl);
        pk[e2] = (short)f2bf((g < 2) ? a0 : a1);
      }
      bf16x8 pf = {pk[0], pk[1], pk[2], pk[3], pk[4], pk[5], pk[6], pk[7]};
      int yx = ((g ^ ((r >> 1) & 3)) << 3);
      __builtin_amdgcn_s_setprio(1);
#pragma unroll
      for (int c2 = 0; c2 < 16; c2++) {  // O^T += V^T . P^T, swizzled LDS reads
        bf16x8 vf = *(const bf16x8*)(vc + (c2 * 16 + r) * 32 + yx);
        o[c2] = __builtin_amdgcn_mfma_f32_16x16x32_bf16(vf, pf, o[c2], 0, 0, 0);
      }
      __builtin_amdgcn_s_setprio(0);
    }
    __syncthreads();
    cur ^= 1;
  }
  float linv = 1.0f / lsum;
  unsigned short* arow = attn + ((size_t)(b * S_LEN) + q0 + w * 16 + r) * (HQ_N * HD_N) + h * HD_N;
#pragma unroll
  for (int c2 = 0; c2 < 16; c2++) {
    unsigned int w0 = (unsigned)f2bf(o[c2][0] * linv) | ((unsigned)f2bf(o[c2][1] * linv) << 16);
    unsigned int w1 = (unsigned)f2bf(o[c2][2] * linv) | ((unsigned)f2bf(o[c2][3] * linv) << 16);
    *(unsigned int*)(arow + c2 * 16 + 4 * g) = w0;
    *(unsigned int*)(arow + c2 * 16 + 4 * g + 2) = w1;
  }
}

extern "C" void kernel_launch(void* const* d_in, const int* in_sizes, int n_in,
                              void* d_out, int out_size, void* d_ws, size_t ws_size,
                              hipStream_t stream) {
  const float* hid  = (const float*)d_in[0];
  const float* cosb = (const float*)d_in[1];
  const float* sinb = (const float*)d_in[2];
  const float* Wq   = (const float*)d_in[4];
  const float* Wk   = (const float*)d_in[5];
  const float* Wv   = (const float*)d_in[6];
  const float* Wo   = (const float*)d_in[7];
  const float* qw   = (const float*)d_in[8];
  const float* kw   = (const float*)d_in[9];

  char* ws = (char*)d_ws;
  unsigned short* Xbf   = (unsigned short*)(ws + 0);            // 4096x2560 bf16
  unsigned short* Wcat  = (unsigned short*)(ws + 20971520);     // 4096x2560 bf16
  unsigned short* Wob   = (unsigned short*)(ws + 41943040);     // 2560x2048 bf16
  unsigned short* QKV   = (unsigned short*)(ws + 52428800);     // 4096x4096 bf16
  unsigned short* qbuf  = (unsigned short*)(ws + 85983232);     // 2*8*2048*256
  unsigned short* kbuf  = (unsigned short*)(ws + 102760448);    // 2*4*2048*256 (tiled)
  unsigned short* vbuf  = (unsigned short*)(ws + 111149056);    // 2*4*2048*256 (tiled)
  unsigned short* attnb = (unsigned short*)(ws + 119537664);    // 4096x2048 bf16
  // total: 136,314,880 B

  // 1) casts
  cvt_kernel<<<10240, 256, 0, stream>>>(hid, Xbf, 2621440);
  cvt_kernel<<<5120, 256, 0, stream>>>(Wq, Wcat, 1310720);
  cvt_kernel<<<2560, 256, 0, stream>>>(Wk, Wcat + 5242880, 655360);
  cvt_kernel<<<2560, 256, 0, stream>>>(Wv, Wcat + 7864320, 655360);
  cvt_kernel<<<5120, 256, 0, stream>>>(Wo, Wob, 1310720);
  // 2) fused QKV projection: QKV = X @ Wcat^T  (grid 16x16 = 256 blocks)
  gemm8p<1><<<256, 512, 0, stream>>>(Xbf, Wcat, QKV, 4096, 4096, 2560, 16);
  // 3) RMSNorm + RoPE (Q pre-scaled; K/V written tiled+swizzled for attn LDS staging)
  rms_rope_kernel<<<16384, 256, 0, stream>>>(QKV, cosb, sinb, qw, kw, qbuf, kbuf, vbuf);
  // 4) sliding-window flash attention
  attn_kernel<<<512, 256, 0, stream>>>(qbuf, kbuf, vbuf, attnb);
  // 5) output projection: d_out = attn @ Wo^T (fp32 out, grid 10x16 = 160 blocks)
  gemm8p<0><<<160, 512, 0, stream>>>(attnb, Wob, (float*)d_out, 4096, 2560, 2048, 10);
}

// Round 6
// 307.878 us; speedup vs baseline: 2.6464x; 1.0448x over previous
//
#include <hip/hip_runtime.h>

#define S_LEN 2048
#define HIDN  2560
#define HQ_N  8
#define HKV_N 4
#define HD_N  256
#define NQKV  4096   // HQ*HD + 2*HKV*HD
#define MROWS 4096   // B*S
#define SC2   0.09016844005556021f  // HD^-0.5 * log2(e), folded into Q at producer

typedef __attribute__((ext_vector_type(8))) short bf16x8;
typedef __attribute__((ext_vector_type(4))) float f32x4;
typedef __attribute__((ext_vector_type(4))) unsigned short u16x4;

typedef const __attribute__((address_space(1))) unsigned int* gas_t;
typedef __attribute__((address_space(3))) unsigned int* las_t;
#define GLDS16(gp, lp) __builtin_amdgcn_global_load_lds((gas_t)(const void*)(gp), \
                                                        (las_t)(void*)(lp), 16, 0, 0)

static __device__ __forceinline__ float bf2f(unsigned short u) {
  unsigned int x = ((unsigned int)u) << 16;
  return __builtin_bit_cast(float, x);
}
static __device__ __forceinline__ unsigned short f2bf(float f) {
  unsigned int u = __builtin_bit_cast(unsigned int, f);
  u += 0x7fffu + ((u >> 16) & 1u);
  return (unsigned short)(u >> 16);
}

// ---------------- fp32 -> bf16 cast (vectorized x4) ----------------
__global__ void cvt_kernel(const float* __restrict__ src,
                           unsigned short* __restrict__ dst, int n4) {
  int i = blockIdx.x * 256 + threadIdx.x;
  if (i >= n4) return;
  f32x4 v = ((const f32x4*)src)[i];
  u16x4 o;
  o[0] = f2bf(v[0]); o[1] = f2bf(v[1]); o[2] = f2bf(v[2]); o[3] = f2bf(v[3]);
  ((u16x4*)dst)[i] = o;
}

// ---------------- 256x256-tile pipelined GEMM, m201-style 4-phase/K-tile -------------
// C[m][n] = sum_k A[m][k]*B[n][k]. 512 thr = 8 waves (2M x 4N), wave tile 128x64.
// BK=64, 2 LDS buffers (128 KB): buf = [A0 16K][A1 16K][B0 16K][B1 16K] bytes.
// LDS swizzle: 16B-slot' = slot ^ (row&7) (8-words/bank minimum on every ds_read_b128).
// GLDS dest linear; global SOURCE inverse-swizzled (rule #21).
// Stage schedule (computing tile u from buf(u&1), ob = other buffer):
//   pha: 12 ds_read (A m0-7 ks0, B ks0)  | stage ob.B0 <- tile(u+1)  | MFMA m0-3 ks0
//   phb:  8 ds_read (A m0-7 ks1)         | stage ob.B1 <- tile(u+1)  | MFMA m4-7 ks0
//        lgkmcnt(0) + s_barrier   (tile-u reads all retired -> cb stage-safe)
//   phc:  4 ds_read (B ks1)              | stage cb.A0 <- tile(u+2)  | MFMA m0-3 ks1
//   phd:                                 | stage cb.A1 <- tile(u+2)  | MFMA m4-7 ks1
//        vmcnt(4 steady / 0 tail) + s_barrier
template <int OUT_BF16>
__global__ __launch_bounds__(512, 2) void gemm8p(const unsigned short* __restrict__ A,
                                                 const unsigned short* __restrict__ B,
                                                 void* __restrict__ C,
                                                 int M, int N, int K, int gx) {
  __shared__ unsigned short ldsw[65536];  // 2 bufs x 32768 elems (128 KB)
  const int tid = threadIdx.x;
  const int lane = tid & 63;
  const int w = tid >> 6;
  const int r = lane & 15, g = lane >> 4;
  const int wr = w >> 2, wc = w & 3;
  const int NT = K >> 6;

  // XCD-aware bijective block swizzle (grid sizes are multiples of 8)
  const int nwg = gridDim.x;
  const int cpx = nwg >> 3;
  const int bid = blockIdx.x;
  const int sbid = (bid & 7) * cpx + (bid >> 3);
  const int bx = sbid % gx, by = sbid / gx;
  const int brow = by * 256, bcol = bx * 256;

  // staging source (inverse-swizzled global column): lane l covers row lr=l>>3,
  // physical slot l&7 -> logical col slot (l&7)^lr
  const int lr = lane >> 3;
  const int lc8 = ((lane & 7) ^ lr) * 8;
  const unsigned short* gA = A + (size_t)(brow + w * 16 + lr) * K + lc8;
  const unsigned short* gB = B + (size_t)(bcol + w * 16 + lr) * K + lc8;
  const size_t rK8 = (size_t)8 * K;
  const size_t rK128 = (size_t)128 * K;
  const int wl = w * 1024;  // per-wave linear LDS stage offset (elems) within a half

  // swizzled ds_read offsets (elems): slot(ks,g,r) = (ks*4+g) ^ (r&7); ks1 = ks0 ^ 4
  const int sl0 = (((g ^ (r & 3)) + 4 * ((r >> 2) & 1))) * 8;
  int aoff[8], boff[4];
#pragma unroll
  for (int mf = 0; mf < 8; mf++) aoff[mf] = wr * 8192 + (mf * 16 + r) * 64 + sl0;
#pragma unroll
  for (int nf = 0; nf < 4; nf++)
    boff[nf] = 16384 + (wc >> 1) * 8192 + ((wc & 1) * 64 + nf * 16 + r) * 64 + sl0;

  f32x4 acc[8][4];
#pragma unroll
  for (int i = 0; i < 8; i++)
#pragma unroll
    for (int j = 0; j < 4; j++) acc[i][j] = (f32x4){0.f, 0.f, 0.f, 0.f};

  // prologue: tile0 {A0,A1,B0,B1} -> buf0 ; tile1 {A0,A1} -> buf1 (12 loads/wave)
  {
    unsigned short* b0 = ldsw;
    unsigned short* b1 = ldsw + 32768;
    GLDS16(gA, b0 + wl);                    GLDS16(gA + rK8, b0 + wl + 512);
    GLDS16(gA + rK128, b0 + 8192 + wl);     GLDS16(gA + rK128 + rK8, b0 + 8192 + wl + 512);
    GLDS16(gB, b0 + 16384 + wl);            GLDS16(gB + rK8, b0 + 16384 + wl + 512);
    GLDS16(gB + rK128, b0 + 24576 + wl);    GLDS16(gB + rK128 + rK8, b0 + 24576 + wl + 512);
    GLDS16(gA + 64, b1 + wl);               GLDS16(gA + 64 + rK8, b1 + wl + 512);
    GLDS16(gA + 64 + rK128, b1 + 8192 + wl); GLDS16(gA + 64 + rK128 + rK8, b1 + 8192 + wl + 512);
  }
  asm volatile("s_waitcnt vmcnt(4)" ::: "memory");
  __builtin_amdgcn_sched_barrier(0);
  __builtin_amdgcn_s_barrier();

  for (int u = 0; u < NT; ++u) {
    const unsigned short* cbp = ldsw + (u & 1) * 32768;
    unsigned short* cbw = ldsw + (u & 1) * 32768;
    unsigned short* obw = ldsw + ((u & 1) ^ 1) * 32768;
    const int c1 = (u + 1) * 64;   // K-col of tile u+1 (B stages)
    const int c2 = (u + 2) * 64;   // K-col of tile u+2 (A stages)
    const bool s1 = (u + 1) < NT, s2 = (u + 2) < NT;

    // ---- pha: reads A(ks0) m0-7 + B(ks0); stage ob.B0; MFMA m0-3 ks0 ----
    bf16x8 af0[4], bk0[4], af1[4];
#pragma unroll
    for (int mf = 0; mf < 4; mf++) af0[mf] = *(const bf16x8*)(cbp + aoff[mf]);
#pragma unroll
    for (int nf = 0; nf < 4; nf++) bk0[nf] = *(const bf16x8*)(cbp + boff[nf]);
#pragma unroll
    for (int mf = 0; mf < 4; mf++) af1[mf] = *(const bf16x8*)(cbp + aoff[4 + mf]);
    if (s1) {
      GLDS16(gB + c1, obw + 16384 + wl);
      GLDS16(gB + c1 + rK8, obw + 16384 + wl + 512);
    }
    __builtin_amdgcn_s_setprio(1);
#pragma unroll
    for (int mf = 0; mf < 4; mf++)
#pragma unroll
      for (int nf = 0; nf < 4; nf++)
        acc[mf][nf] = __builtin_amdgcn_mfma_f32_16x16x32_bf16(af0[mf], bk0[nf], acc[mf][nf], 0, 0, 0);
    __builtin_amdgcn_s_setprio(0);

    // ---- phb: reads A(ks1) m0-7; stage ob.B1; MFMA m4-7 ks0 ----
    bf16x8 ag0[4], ag1[4];
#pragma unroll
    for (int mf = 0; mf < 4; mf++) ag0[mf] = *(const bf16x8*)(cbp + (aoff[mf] ^ 32));
#pragma unroll
    for (int mf = 0; mf < 4; mf++) ag1[mf] = *(const bf16x8*)(cbp + (aoff[4 + mf] ^ 32));
    if (s1) {
      GLDS16(gB + c1 + rK128, obw + 24576 + wl);
      GLDS16(gB + c1 + rK128 + rK8, obw + 24576 + wl + 512);
    }
    __builtin_amdgcn_s_setprio(1);
#pragma unroll
    for (int mf = 0; mf < 4; mf++)
#pragma unroll
      for (int nf = 0; nf < 4; nf++)
        acc[4 + mf][nf] = __builtin_amdgcn_mfma_f32_16x16x32_bf16(af1[mf], bk0[nf], acc[4 + mf][nf], 0, 0, 0);
    __builtin_amdgcn_s_setprio(0);
    asm volatile("s_waitcnt lgkmcnt(0)" ::: "memory");
    __builtin_amdgcn_sched_barrier(0);
    __builtin_amdgcn_s_barrier();

    // ---- phc: reads B(ks1); stage cb.A0 <- tile u+2; MFMA m0-3 ks1 ----
    bf16x8 bk1[4];
#pragma unroll
    for (int nf = 0; nf < 4; nf++) bk1[nf] = *(const bf16x8*)(cbp + (boff[nf] ^ 32));
    if (s2) {
      GLDS16(gA + c2, cbw + wl);
      GLDS16(gA + c2 + rK8, cbw + wl + 512);
    }
    __builtin_amdgcn_s_setprio(1);
#pragma unroll
    for (int mf = 0; mf < 4; mf++)
#pragma unroll
      for (int nf = 0; nf < 4; nf++)
        acc[mf][nf] = __builtin_amdgcn_mfma_f32_16x16x32_bf16(ag0[mf], bk1[nf], acc[mf][nf], 0, 0, 0);
    __builtin_amdgcn_s_setprio(0);

    // ---- phd: stage cb.A1 <- tile u+2; MFMA m4-7 ks1 ----
    if (s2) {
      GLDS16(gA + c2 + rK128, cbw + 8192 + wl);
      GLDS16(gA + c2 + rK128 + rK8, cbw + 8192 + wl + 512);
    }
    __builtin_amdgcn_s_setprio(1);
#pragma unroll
    for (int mf = 0; mf < 4; mf++)
#pragma unroll
      for (int nf = 0; nf < 4; nf++)
        acc[4 + mf][nf] = __builtin_amdgcn_mfma_f32_16x16x32_bf16(ag1[mf], bk1[nf], acc[4 + mf][nf], 0, 0, 0);
    __builtin_amdgcn_s_setprio(0);
    if (s2) { asm volatile("s_waitcnt vmcnt(4)" ::: "memory"); }
    else    { asm volatile("s_waitcnt vmcnt(0)" ::: "memory"); }
    __builtin_amdgcn_sched_barrier(0);
    __builtin_amdgcn_s_barrier();
  }

  // epilogue: acc[m][n] -> C[brow + wr*128 + m*16 + g*4 + e][bcol + wc*64 + n*16 + r]
#pragma unroll
  for (int i = 0; i < 8; i++)
#pragma unroll
    for (int j = 0; j < 4; j++) {
      const int col = bcol + wc * 64 + j * 16 + r;
      const int rowb = brow + wr * 128 + i * 16 + g * 4;
#pragma unroll
      for (int e = 0; e < 4; e++) {
        if (OUT_BF16)
          ((unsigned short*)C)[(size_t)(rowb + e) * N + col] = f2bf(acc[i][j][e]);
        else
          ((float*)C)[(size_t)(rowb + e) * N + col] = acc[i][j][e];
      }
    }
}

// ---------------- fused RMSNorm (+weight) + RoPE ----------------
// q: [b][h][s][d] row-major bf16, PRE-SCALED by SC2 (softmax scale folded in).
// k: per-32-key tiled slabs, slot pre-swizzled: slot' = (d>>3) ^ (kr&7)
// v: per-32-key tiled slabs, slot pre-swizzled: slot' = (ks>>3) ^ ((d>>1)&3)
__global__ __launch_bounds__(256) void rms_rope_kernel(
    const unsigned short* __restrict__ qkv, const float* __restrict__ cosb,
    const float* __restrict__ sinb, const float* __restrict__ qw,
    const float* __restrict__ kw, unsigned short* __restrict__ qo,
    unsigned short* __restrict__ ko, unsigned short* __restrict__ vo) {
  int wid = (blockIdx.x * 256 + threadIdx.x) >> 6;
  int lane = threadIdx.x & 63;
  int row = wid >> 4;   // 0..4095 (= b*2048 + s)
  int unit = wid & 15;  // 0..7 q heads, 8..11 k heads, 12..15 v heads
  int b = row >> 11, s = row & 2047;
  int d0 = lane * 4;
  const unsigned short* x = qkv + (size_t)row * NQKV + unit * HD_N + d0;
  u16x4 xb = *(const u16x4*)x;
  float v[4];
#pragma unroll
  for (int j = 0; j < 4; j++) v[j] = bf2f(xb[j]);
  float ss = v[0] * v[0] + v[1] * v[1] + v[2] * v[2] + v[3] * v[3];
#pragma unroll
  for (int off = 32; off >= 1; off >>= 1) ss += __shfl_xor(ss, off);
  float inv = 1.0f / sqrtf(ss * (1.0f / 256.0f) + 1e-6f);

  int kb = s >> 5;
  if (unit >= 12) {  // v: norm only, tiled+swizzled
    int hv = unit - 12;
    int ks = s & 31;
    unsigned short* slab = vo + ((size_t)(b * HKV_N + hv) * 64 + kb) * 8192;
#pragma unroll
    for (int j = 0; j < 4; j++) {
      int d = d0 + j;
      int pos = d * 32 + (((ks >> 3) ^ ((d >> 1) & 3)) << 3) + (ks & 7);
      slab[pos] = f2bf(v[j] * inv);
    }
    return;
  }
  const float* wv = (unit < 8) ? qw : kw;
  const float qsc = (unit < 8) ? SC2 : 1.0f;  // fold softmax scale into Q
  f32x4 wl = *(const f32x4*)(wv + d0);
  float y[4];
#pragma unroll
  for (int j = 0; j < 4; j++) y[j] = v[j] * inv * wl[j] * qsc;
  float yp[4];
#pragma unroll
  for (int j = 0; j < 4; j++) yp[j] = __shfl_xor(y[j], 32);  // element at d ^ 128
  f32x4 cv = *(const f32x4*)(cosb + (size_t)row * HD_N + d0);
  f32x4 sv = *(const f32x4*)(sinb + (size_t)row * HD_N + d0);
  u16x4 out;
#pragma unroll
  for (int j = 0; j < 4; j++) {
    float rot = (d0 < 128) ? -yp[j] : yp[j];
    out[j] = f2bf(y[j] * cv[j] + rot * sv[j]);
  }
  if (unit < 8) {
    unsigned short* dst = qo + ((size_t)(b * HQ_N + unit) * S_LEN + s) * HD_N + d0;
    *(u16x4*)dst = out;
  } else {
    int kv = unit - 8;
    int kr = s & 31;
    unsigned short* dst = ko + ((size_t)(b * HKV_N + kv) * 64 + kb) * 8192 + kr * 256 +
                          (((d0 >> 3) ^ (kr & 7)) << 3) + (d0 & 7);
    *(u16x4*)dst = out;
  }
}

// ---------------- flash attention: 4 waves/block, QBLK=64, K/V LDS double-buffered ------
__global__ __launch_bounds__(256) void attn_kernel(const unsigned short* __restrict__ qb,
                                                   const unsigned short* __restrict__ kb_,
                                                   const unsigned short* __restrict__ vb_,
                                                   unsigned short* __restrict__ attn) {
  __shared__ unsigned short kt[2][8192];
  __shared__ unsigned short vt[2][8192];
  const int lane = threadIdx.x & 63;
  const int w = threadIdx.x >> 6;
  const int r = lane & 15, g = lane >> 4;
  const int pblk = blockIdx.x;
  const int lb = (pblk & 7) * 64 + (pblk >> 3);  // XCD chunk = 64 blocks = one (b,kvh)
  const int qt = lb & 31;
  const int h = (lb >> 5) & 7;
  const int b = lb >> 8;
  const int kvh = h >> 1;
  const int q0 = qt * 64;
  const int qi = q0 + w * 16 + r;  // this lane's q-row
  const int wqmin = q0 + w * 16, wqmax = wqmin + 15;
  const unsigned short* qbase = qb + ((size_t)(b * HQ_N + h) * S_LEN + q0 + w * 16) * HD_N;
  const unsigned short* kslabs = kb_ + (size_t)(b * HKV_N + kvh) * S_LEN * HD_N;
  const unsigned short* vslabs = vb_ + (size_t)(b * HKV_N + kvh) * S_LEN * HD_N;

  bf16x8 qf[8];
#pragma unroll
  for (int c = 0; c < 8; c++)
    qf[c] = *(const bf16x8*)(qbase + (size_t)r * HD_N + c * 32 + g * 8);

  f32x4 o[16];
#pragma unroll
  for (int i = 0; i < 16; i++) o[i] = (f32x4){0.f, 0.f, 0.f, 0.f};
  float m = -1e30f, lsum = 0.0f;

  int lo = q0 - 1023; if (lo < 0) lo = 0; lo &= ~31;
  const int hiend = q0 + 64;

  // prologue stage
  {
    const unsigned short* ks = kslabs + (size_t)(lo >> 5) * 8192 + w * 2048;
    const unsigned short* vs = vslabs + (size_t)(lo >> 5) * 8192 + w * 2048;
#pragma unroll
    for (int j = 0; j < 4; j++) {
      GLDS16(ks + j * 512 + lane * 8, &kt[0][w * 2048 + j * 512]);
      GLDS16(vs + j * 512 + lane * 8, &vt[0][w * 2048 + j * 512]);
    }
  }
  __syncthreads();

  int cur = 0;
  for (int key0 = lo; key0 < hiend; key0 += 32) {
    if (key0 + 32 < hiend) {
      const unsigned short* ks = kslabs + (size_t)((key0 + 32) >> 5) * 8192 + w * 2048;
      const unsigned short* vs = vslabs + (size_t)((key0 + 32) >> 5) * 8192 + w * 2048;
#pragma unroll
      for (int j = 0; j < 4; j++) {
        GLDS16(ks + j * 512 + lane * 8, &kt[cur ^ 1][w * 2048 + j * 512]);
        GLDS16(vs + j * 512 + lane * 8, &vt[cur ^ 1][w * 2048 + j * 512]);
      }
    }
    // wave-level skip: tile outside this wave's 16-row window union
    if (key0 <= wqmax && key0 + 31 >= wqmin - 1023) {
      const unsigned short* kc = kt[cur];
      const unsigned short* vc = vt[cur];

      f32x4 st0 = (f32x4){0.f, 0.f, 0.f, 0.f}, st1 = (f32x4){0.f, 0.f, 0.f, 0.f};
      __builtin_amdgcn_s_setprio(1);
#pragma unroll
      for (int c = 0; c < 8; c++) {  // S^T = K . Q^T over HD, swizzled LDS reads
        int x0 = (((c * 4 + g) ^ (r & 7)) << 3);
        bf16x8 kf0 = *(const bf16x8*)(kc + r * 256 + x0);
        bf16x8 kf1 = *(const bf16x8*)(kc + (16 + r) * 256 + x0);
        st0 = __builtin_amdgcn_mfma_f32_16x16x32_bf16(kf0, qf[c], st0, 0, 0, 0);
        st1 = __builtin_amdgcn_mfma_f32_16x16x32_bf16(kf1, qf[c], st1, 0, 0, 0);
      }
      __builtin_amdgcn_s_setprio(0);
      float p[2][4];
      float pm = -3e30f;
#pragma unroll
      for (int t = 0; t < 2; t++)
#pragma unroll
        for (int e = 0; e < 4; e++) {
          int key = key0 + t * 16 + 4 * g + e;
          float sv = (t == 0 ? st0[e] : st1[e]);  // scale pre-folded into Q
          sv = (key <= qi && key > qi - 1024) ? sv : -2e30f;  // window mask
          p[t][e] = sv;
          pm = fmaxf(pm, sv);
        }
      pm = fmaxf(pm, __shfl_xor(pm, 16));
      pm = fmaxf(pm, __shfl_xor(pm, 32));
      // defer-max: skip O-rescale when max didn't grow by >8 (exp2 headroom 2^8)
      if (!__all(pm <= m + 8.0f)) {
        float newm = fmaxf(m, pm);
        float f = exp2f(m - newm);
        m = newm;
        lsum *= f;
#pragma unroll
        for (int i = 0; i < 16; i++) {
          o[i][0] *= f; o[i][1] *= f; o[i][2] *= f; o[i][3] *= f;
        }
      }
      float ps = 0.0f;
#pragma unroll
      for (int t = 0; t < 2; t++)
#pragma unroll
        for (int e = 0; e < 4; e++) {
          float pe = exp2f(p[t][e] - m);
          p[t][e] = pe;
          ps += pe;
        }
      ps += __shfl_xor(ps, 16);
      ps += __shfl_xor(ps, 32);
      lsum += ps;
      short pk[8];
#pragma unroll
      for (int e2 = 0; e2 < 8; e2++) {
        int srcl = r + 16 * (2 * (g & 1) + (e2 >> 2));
        float a0 = __shfl(p[0][e2 & 3], srcl);
        float a1 = __shfl(p[1][e2 & 3], srcl);
        pk[e2] = (short)f2bf((g < 2) ? a0 : a1);
      }
      bf16x8 pf = {pk[0], pk[1], pk[2], pk[3], pk[4], pk[5], pk[6], pk[7]};
      int yx = ((g ^ ((r >> 1) & 3)) << 3);
      __builtin_amdgcn_s_setprio(1);
#pragma unroll
      for (int c2 = 0; c2 < 16; c2++) {  // O^T += V^T . P^T, swizzled LDS reads
        bf16x8 vf = *(const bf16x8*)(vc + (c2 * 16 + r) * 32 + yx);
        o[c2] = __builtin_amdgcn_mfma_f32_16x16x32_bf16(vf, pf, o[c2], 0, 0, 0);
      }
      __builtin_amdgcn_s_setprio(0);
    }
    __syncthreads();
    cur ^= 1;
  }
  float linv = 1.0f / lsum;
  unsigned short* arow = attn + ((size_t)(b * S_LEN) + q0 + w * 16 + r) * (HQ_N * HD_N) + h * HD_N;
#pragma unroll
  for (int c2 = 0; c2 < 16; c2++) {
    unsigned int w0 = (unsigned)f2bf(o[c2][0] * linv) | ((unsigned)f2bf(o[c2][1] * linv) << 16);
    unsigned int w1 = (unsigned)f2bf(o[c2][2] * linv) | ((unsigned)f2bf(o[c2][3] * linv) << 16);
    *(unsigned int*)(arow + c2 * 16 + 4 * g) = w0;
    *(unsigned int*)(arow + c2 * 16 + 4 * g + 2) = w1;
  }
}

extern "C" void kernel_launch(void* const* d_in, const int* in_sizes, int n_in,
                              void* d_out, int out_size, void* d_ws, size_t ws_size,
                              hipStream_t stream) {
  const float* hid  = (const float*)d_in[0];
  const float* cosb = (const float*)d_in[1];
  const float* sinb = (const float*)d_in[2];
  const float* Wq   = (const float*)d_in[4];
  const float* Wk   = (const float*)d_in[5];
  const float* Wv   = (const float*)d_in[6];
  const float* Wo   = (const float*)d_in[7];
  const float* qw   = (const float*)d_in[8];
  const float* kw   = (const float*)d_in[9];

  char* ws = (char*)d_ws;
  unsigned short* Xbf   = (unsigned short*)(ws + 0);            // 4096x2560 bf16
  unsigned short* Wcat  = (unsigned short*)(ws + 20971520);     // 4096x2560 bf16
  unsigned short* Wob   = (unsigned short*)(ws + 41943040);     // 2560x2048 bf16
  unsigned short* QKV   = (unsigned short*)(ws + 52428800);     // 4096x4096 bf16
  unsigned short* qbuf  = (unsigned short*)(ws + 85983232);     // 2*8*2048*256
  unsigned short* kbuf  = (unsigned short*)(ws + 102760448);    // 2*4*2048*256 (tiled)
  unsigned short* vbuf  = (unsigned short*)(ws + 111149056);    // 2*4*2048*256 (tiled)
  unsigned short* attnb = (unsigned short*)(ws + 119537664);    // 4096x2048 bf16
  // total: 136,314,880 B

  // 1) casts
  cvt_kernel<<<10240, 256, 0, stream>>>(hid, Xbf, 2621440);
  cvt_kernel<<<5120, 256, 0, stream>>>(Wq, Wcat, 1310720);
  cvt_kernel<<<2560, 256, 0, stream>>>(Wk, Wcat + 5242880, 655360);
  cvt_kernel<<<2560, 256, 0, stream>>>(Wv, Wcat + 7864320, 655360);
  cvt_kernel<<<5120, 256, 0, stream>>>(Wo, Wob, 1310720);
  // 2) fused QKV projection: QKV = X @ Wcat^T  (grid 16x16 = 256 blocks, NT=40)
  gemm8p<1><<<256, 512, 0, stream>>>(Xbf, Wcat, QKV, 4096, 4096, 2560, 16);
  // 3) RMSNorm + RoPE (Q pre-scaled; K/V written tiled+swizzled for attn LDS staging)
  rms_rope_kernel<<<16384, 256, 0, stream>>>(QKV, cosb, sinb, qw, kw, qbuf, kbuf, vbuf);
  // 4) sliding-window flash attention
  attn_kernel<<<512, 256, 0, stream>>>(qbuf, kbuf, vbuf, attnb);
  // 5) output projection: d_out = attn @ Wo^T (fp32 out, grid 10x16 = 160 blocks, NT=32)
  gemm8p<0><<<160, 512, 0, stream>>>(attnb, Wob, (float*)d_out, 4096, 2560, 2048, 10);
}

// Round 7
// 291.782 us; speedup vs baseline: 2.7924x; 1.0552x over previous
//
#include <hip/hip_runtime.h>

#define S_LEN 2048
#define HIDN  2560
#define HQ_N  8
#define HKV_N 4
#define HD_N  256
#define NQKV  4096   // HQ*HD + 2*HKV*HD
#define MROWS 4096   // B*S
#define SC2   0.09016844005556021f  // HD^-0.5 * log2(e), folded into Q at producer

typedef __attribute__((ext_vector_type(8))) short bf16x8;
typedef __attribute__((ext_vector_type(4))) float f32x4;
typedef __attribute__((ext_vector_type(4))) unsigned short u16x4;

typedef const __attribute__((address_space(1))) unsigned int* gas_t;
typedef __attribute__((address_space(3))) unsigned int* las_t;
#define GLDS16(gp, lp) __builtin_amdgcn_global_load_lds((gas_t)(const void*)(gp), \
                                                        (las_t)(void*)(lp), 16, 0, 0)

static __device__ __forceinline__ float bf2f(unsigned short u) {
  unsigned int x = ((unsigned int)u) << 16;
  return __builtin_bit_cast(float, x);
}
static __device__ __forceinline__ unsigned short f2bf(float f) {
  unsigned int u = __builtin_bit_cast(unsigned int, f);
  u += 0x7fffu + ((u >> 16) & 1u);
  return (unsigned short)(u >> 16);
}

// ---------------- merged fp32 -> bf16 cast for all 5 tensors (one launch) ----------------
// ranges (vec4 units): X 2621440 | Wq 1310720 | Wk 655360 | Wv 655360 | Wo 1310720
// all boundaries are multiples of 256 -> branch is block-uniform.
__global__ void cvt_all_kernel(const float* __restrict__ hid, const float* __restrict__ Wq,
                               const float* __restrict__ Wk, const float* __restrict__ Wv,
                               const float* __restrict__ Wo, unsigned short* __restrict__ Xbf,
                               unsigned short* __restrict__ Wcat,
                               unsigned short* __restrict__ Wob) {
  int i = blockIdx.x * 256 + threadIdx.x;
  const float* src;
  unsigned short* dst;
  int j;
  if (i < 2621440) { src = hid; dst = Xbf; j = i; }
  else if (i < 3932160) { src = Wq; dst = Wcat; j = i - 2621440; }
  else if (i < 4587520) { src = Wk; dst = Wcat + 5242880; j = i - 3932160; }
  else if (i < 5242880) { src = Wv; dst = Wcat + 7864320; j = i - 4587520; }
  else { src = Wo; dst = Wob; j = i - 5242880; }
  f32x4 v = ((const f32x4*)src)[j];
  u16x4 o;
  o[0] = f2bf(v[0]); o[1] = f2bf(v[1]); o[2] = f2bf(v[2]); o[3] = f2bf(v[3]);
  ((u16x4*)dst)[j] = o;
}

// ---------------- 256x256-tile pipelined GEMM, 4-phase/K-tile -------------
template <int OUT_BF16>
__global__ __launch_bounds__(512, 2) void gemm8p(const unsigned short* __restrict__ A,
                                                 const unsigned short* __restrict__ B,
                                                 void* __restrict__ C,
                                                 int M, int N, int K, int gx) {
  __shared__ unsigned short ldsw[65536];  // 2 bufs x 32768 elems (128 KB)
  const int tid = threadIdx.x;
  const int lane = tid & 63;
  const int w = tid >> 6;
  const int r = lane & 15, g = lane >> 4;
  const int wr = w >> 2, wc = w & 3;
  const int NT = K >> 6;

  const int nwg = gridDim.x;
  const int cpx = nwg >> 3;
  const int bid = blockIdx.x;
  const int sbid = (bid & 7) * cpx + (bid >> 3);
  const int bx = sbid % gx, by = sbid / gx;
  const int brow = by * 256, bcol = bx * 256;

  const int lr = lane >> 3;
  const int lc8 = ((lane & 7) ^ lr) * 8;
  const unsigned short* gA = A + (size_t)(brow + w * 16 + lr) * K + lc8;
  const unsigned short* gB = B + (size_t)(bcol + w * 16 + lr) * K + lc8;
  const size_t rK8 = (size_t)8 * K;
  const size_t rK128 = (size_t)128 * K;
  const int wl = w * 1024;

  const int sl0 = (((g ^ (r & 3)) + 4 * ((r >> 2) & 1))) * 8;
  int aoff[8], boff[4];
#pragma unroll
  for (int mf = 0; mf < 8; mf++) aoff[mf] = wr * 8192 + (mf * 16 + r) * 64 + sl0;
#pragma unroll
  for (int nf = 0; nf < 4; nf++)
    boff[nf] = 16384 + (wc >> 1) * 8192 + ((wc & 1) * 64 + nf * 16 + r) * 64 + sl0;

  f32x4 acc[8][4];
#pragma unroll
  for (int i = 0; i < 8; i++)
#pragma unroll
    for (int j = 0; j < 4; j++) acc[i][j] = (f32x4){0.f, 0.f, 0.f, 0.f};

  {
    unsigned short* b0 = ldsw;
    unsigned short* b1 = ldsw + 32768;
    GLDS16(gA, b0 + wl);                    GLDS16(gA + rK8, b0 + wl + 512);
    GLDS16(gA + rK128, b0 + 8192 + wl);     GLDS16(gA + rK128 + rK8, b0 + 8192 + wl + 512);
    GLDS16(gB, b0 + 16384 + wl);            GLDS16(gB + rK8, b0 + 16384 + wl + 512);
    GLDS16(gB + rK128, b0 + 24576 + wl);    GLDS16(gB + rK128 + rK8, b0 + 24576 + wl + 512);
    GLDS16(gA + 64, b1 + wl);               GLDS16(gA + 64 + rK8, b1 + wl + 512);
    GLDS16(gA + 64 + rK128, b1 + 8192 + wl); GLDS16(gA + 64 + rK128 + rK8, b1 + 8192 + wl + 512);
  }
  asm volatile("s_waitcnt vmcnt(4)" ::: "memory");
  __builtin_amdgcn_sched_barrier(0);
  __builtin_amdgcn_s_barrier();

  for (int u = 0; u < NT; ++u) {
    const unsigned short* cbp = ldsw + (u & 1) * 32768;
    unsigned short* cbw = ldsw + (u & 1) * 32768;
    unsigned short* obw = ldsw + ((u & 1) ^ 1) * 32768;
    const int c1 = (u + 1) * 64;
    const int c2 = (u + 2) * 64;
    const bool s1 = (u + 1) < NT, s2 = (u + 2) < NT;

    bf16x8 af0[4], bk0[4], af1[4];
#pragma unroll
    for (int mf = 0; mf < 4; mf++) af0[mf] = *(const bf16x8*)(cbp + aoff[mf]);
#pragma unroll
    for (int nf = 0; nf < 4; nf++) bk0[nf] = *(const bf16x8*)(cbp + boff[nf]);
#pragma unroll
    for (int mf = 0; mf < 4; mf++) af1[mf] = *(const bf16x8*)(cbp + aoff[4 + mf]);
    if (s1) {
      GLDS16(gB + c1, obw + 16384 + wl);
      GLDS16(gB + c1 + rK8, obw + 16384 + wl + 512);
    }
    __builtin_amdgcn_s_setprio(1);
#pragma unroll
    for (int mf = 0; mf < 4; mf++)
#pragma unroll
      for (int nf = 0; nf < 4; nf++)
        acc[mf][nf] = __builtin_amdgcn_mfma_f32_16x16x32_bf16(af0[mf], bk0[nf], acc[mf][nf], 0, 0, 0);
    __builtin_amdgcn_s_setprio(0);

    bf16x8 ag0[4], ag1[4];
#pragma unroll
    for (int mf = 0; mf < 4; mf++) ag0[mf] = *(const bf16x8*)(cbp + (aoff[mf] ^ 32));
#pragma unroll
    for (int mf = 0; mf < 4; mf++) ag1[mf] = *(const bf16x8*)(cbp + (aoff[4 + mf] ^ 32));
    if (s1) {
      GLDS16(gB + c1 + rK128, obw + 24576 + wl);
      GLDS16(gB + c1 + rK128 + rK8, obw + 24576 + wl + 512);
    }
    __builtin_amdgcn_s_setprio(1);
#pragma unroll
    for (int mf = 0; mf < 4; mf++)
#pragma unroll
      for (int nf = 0; nf < 4; nf++)
        acc[4 + mf][nf] = __builtin_amdgcn_mfma_f32_16x16x32_bf16(af1[mf], bk0[nf], acc[4 + mf][nf], 0, 0, 0);
    __builtin_amdgcn_s_setprio(0);
    asm volatile("s_waitcnt lgkmcnt(0)" ::: "memory");
    __builtin_amdgcn_sched_barrier(0);
    __builtin_amdgcn_s_barrier();

    bf16x8 bk1[4];
#pragma unroll
    for (int nf = 0; nf < 4; nf++) bk1[nf] = *(const bf16x8*)(cbp + (boff[nf] ^ 32));
    if (s2) {
      GLDS16(gA + c2, cbw + wl);
      GLDS16(gA + c2 + rK8, cbw + wl + 512);
    }
    __builtin_amdgcn_s_setprio(1);
#pragma unroll
    for (int mf = 0; mf < 4; mf++)
#pragma unroll
      for (int nf = 0; nf < 4; nf++)
        acc[mf][nf] = __builtin_amdgcn_mfma_f32_16x16x32_bf16(ag0[mf], bk1[nf], acc[mf][nf], 0, 0, 0);
    __builtin_amdgcn_s_setprio(0);

    if (s2) {
      GLDS16(gA + c2 + rK128, cbw + 8192 + wl);
      GLDS16(gA + c2 + rK128 + rK8, cbw + 8192 + wl + 512);
    }
    __builtin_amdgcn_s_setprio(1);
#pragma unroll
    for (int mf = 0; mf < 4; mf++)
#pragma unroll
      for (int nf = 0; nf < 4; nf++)
        acc[4 + mf][nf] = __builtin_amdgcn_mfma_f32_16x16x32_bf16(ag1[mf], bk1[nf], acc[4 + mf][nf], 0, 0, 0);
    __builtin_amdgcn_s_setprio(0);
    if (s2) { asm volatile("s_waitcnt vmcnt(4)" ::: "memory"); }
    else    { asm volatile("s_waitcnt vmcnt(0)" ::: "memory"); }
    __builtin_amdgcn_sched_barrier(0);
    __builtin_amdgcn_s_barrier();
  }

#pragma unroll
  for (int i = 0; i < 8; i++)
#pragma unroll
    for (int j = 0; j < 4; j++) {
      const int col = bcol + wc * 64 + j * 16 + r;
      const int rowb = brow + wr * 128 + i * 16 + g * 4;
#pragma unroll
      for (int e = 0; e < 4; e++) {
        if (OUT_BF16)
          ((unsigned short*)C)[(size_t)(rowb + e) * N + col] = f2bf(acc[i][j][e]);
        else
          ((float*)C)[(size_t)(rowb + e) * N + col] = acc[i][j][e];
      }
    }
}

// ---------------- fused RMSNorm (+weight) + RoPE ----------------
__global__ __launch_bounds__(256) void rms_rope_kernel(
    const unsigned short* __restrict__ qkv, const float* __restrict__ cosb,
    const float* __restrict__ sinb, const float* __restrict__ qw,
    const float* __restrict__ kw, unsigned short* __restrict__ qo,
    unsigned short* __restrict__ ko, unsigned short* __restrict__ vo) {
  int wid = (blockIdx.x * 256 + threadIdx.x) >> 6;
  int lane = threadIdx.x & 63;
  int row = wid >> 4;   // 0..4095 (= b*2048 + s)
  int unit = wid & 15;  // 0..7 q heads, 8..11 k heads, 12..15 v heads
  int b = row >> 11, s = row & 2047;
  int d0 = lane * 4;
  const unsigned short* x = qkv + (size_t)row * NQKV + unit * HD_N + d0;
  u16x4 xb = *(const u16x4*)x;
  float v[4];
#pragma unroll
  for (int j = 0; j < 4; j++) v[j] = bf2f(xb[j]);
  float ss = v[0] * v[0] + v[1] * v[1] + v[2] * v[2] + v[3] * v[3];
#pragma unroll
  for (int off = 32; off >= 1; off >>= 1) ss += __shfl_xor(ss, off);
  float inv = 1.0f / sqrtf(ss * (1.0f / 256.0f) + 1e-6f);

  int kb = s >> 5;
  if (unit >= 12) {  // v: norm only, tiled+swizzled
    int hv = unit - 12;
    int ks = s & 31;
    unsigned short* slab = vo + ((size_t)(b * HKV_N + hv) * 64 + kb) * 8192;
#pragma unroll
    for (int j = 0; j < 4; j++) {
      int d = d0 + j;
      int pos = d * 32 + (((ks >> 3) ^ ((d >> 1) & 3)) << 3) + (ks & 7);
      slab[pos] = f2bf(v[j] * inv);
    }
    return;
  }
  const float* wv = (unit < 8) ? qw : kw;
  const float qsc = (unit < 8) ? SC2 : 1.0f;  // fold softmax scale into Q
  f32x4 wl = *(const f32x4*)(wv + d0);
  float y[4];
#pragma unroll
  for (int j = 0; j < 4; j++) y[j] = v[j] * inv * wl[j] * qsc;
  float yp[4];
#pragma unroll
  for (int j = 0; j < 4; j++) yp[j] = __shfl_xor(y[j], 32);  // element at d ^ 128
  f32x4 cv = *(const f32x4*)(cosb + (size_t)row * HD_N + d0);
  f32x4 sv = *(const f32x4*)(sinb + (size_t)row * HD_N + d0);
  u16x4 out;
#pragma unroll
  for (int j = 0; j < 4; j++) {
    float rot = (d0 < 128) ? -yp[j] : yp[j];
    out[j] = f2bf(y[j] * cv[j] + rot * sv[j]);
  }
  if (unit < 8) {
    unsigned short* dst = qo + ((size_t)(b * HQ_N + unit) * S_LEN + s) * HD_N + d0;
    *(u16x4*)dst = out;
  } else {
    int kv = unit - 8;
    int kr = s & 31;
    unsigned short* dst = ko + ((size_t)(b * HKV_N + kv) * 64 + kb) * 8192 + kr * 256 +
                          (((d0 >> 3) ^ (kr & 7)) << 3) + (d0 & 7);
    *(u16x4*)dst = out;
  }
}

// ---------------- flash attention: GQA-paired 8-wave blocks, QBLK=64, KVBLK=64 ---------
// Block = both heads of one kvh group x 4 waves x 16 q-rows. K/V staged ONCE for 2 heads.
// LDS 128 KB double-buffered (1 block/CU, 8 waves). XCD chunk (32 blocks) = one (b,kvh).
__global__ __launch_bounds__(512) void attn_kernel(const unsigned short* __restrict__ qb,
                                                   const unsigned short* __restrict__ kb_,
                                                   const unsigned short* __restrict__ vb_,
                                                   unsigned short* __restrict__ attn) {
  __shared__ unsigned short kt[2][16384];
  __shared__ unsigned short vt[2][16384];
  const int lane = threadIdx.x & 63;
  const int w = threadIdx.x >> 6;   // 0..7
  const int r = lane & 15, g = lane >> 4;
  const int pblk = blockIdx.x;
  const int lb = (pblk & 7) * 32 + (pblk >> 3);  // XCD chunk = 32 blocks = one (b,kvh)
  const int qt = lb & 31;
  const int kvh = (lb >> 5) & 3;
  const int b = lb >> 7;
  const int h = kvh * 2 + (w >> 2);  // wave's head within the GQA pair
  const int ww = w & 3;              // wave-in-head
  const int q0 = qt * 64;
  const int qi = q0 + ww * 16 + r;   // this lane's q-row
  const int wqmin = q0 + ww * 16, wqmax = wqmin + 15;
  const unsigned short* qbase = qb + ((size_t)(b * HQ_N + h) * S_LEN + q0 + ww * 16) * HD_N;
  const unsigned short* kslabs = kb_ + (size_t)(b * HKV_N + kvh) * S_LEN * HD_N;
  const unsigned short* vslabs = vb_ + (size_t)(b * HKV_N + kvh) * S_LEN * HD_N;

  bf16x8 qf[8];
#pragma unroll
  for (int c = 0; c < 8; c++)
    qf[c] = *(const bf16x8*)(qbase + (size_t)r * HD_N + c * 32 + g * 8);

  f32x4 o[16];
#pragma unroll
  for (int i = 0; i < 16; i++) o[i] = (f32x4){0.f, 0.f, 0.f, 0.f};
  float m = -1e30f, lsum = 0.0f;

  int lo = q0 - 1023; if (lo < 0) lo = 0; lo &= ~63;
  const int hiend = q0 + 64;

  // prologue: stage 64-key tile (lo>>6); per thread 4 K + 4 V GLDS16
  {
    const unsigned short* ks = kslabs + (size_t)(lo >> 6) * 16384;
    const unsigned short* vs = vslabs + (size_t)(lo >> 6) * 16384;
#pragma unroll
    for (int j = 0; j < 4; j++) {
      GLDS16(ks + j * 4096 + w * 512 + lane * 8, &kt[0][j * 4096 + w * 512]);
      GLDS16(vs + j * 4096 + w * 512 + lane * 8, &vt[0][j * 4096 + w * 512]);
    }
  }
  __syncthreads();

  int cur = 0;
  for (int kk = lo; kk < hiend; kk += 64) {
    if (kk + 64 < hiend) {
      const unsigned short* ks = kslabs + (size_t)((kk >> 6) + 1) * 16384;
      const unsigned short* vs = vslabs + (size_t)((kk >> 6) + 1) * 16384;
#pragma unroll
      for (int j = 0; j < 4; j++) {
        GLDS16(ks + j * 4096 + w * 512 + lane * 8, &kt[cur ^ 1][j * 4096 + w * 512]);
        GLDS16(vs + j * 4096 + w * 512 + lane * 8, &vt[cur ^ 1][j * 4096 + w * 512]);
      }
    }
#pragma unroll
    for (int s = 0; s < 2; s++) {
      const int key0 = kk + s * 32;
      // wave-level skip: subtile outside this wave's 16-row window union
      if (key0 <= wqmax && key0 + 31 >= wqmin - 1023) {
        const unsigned short* kc = &kt[cur][s * 8192];
        const unsigned short* vc = &vt[cur][s * 8192];

        f32x4 st0 = (f32x4){0.f, 0.f, 0.f, 0.f}, st1 = (f32x4){0.f, 0.f, 0.f, 0.f};
        __builtin_amdgcn_s_setprio(1);
#pragma unroll
        for (int c = 0; c < 8; c++) {  // S^T = K . Q^T over HD, swizzled LDS reads
          int x0 = (((c * 4 + g) ^ (r & 7)) << 3);
          bf16x8 kf0 = *(const bf16x8*)(kc + r * 256 + x0);
          bf16x8 kf1 = *(const bf16x8*)(kc + (16 + r) * 256 + x0);
          st0 = __builtin_amdgcn_mfma_f32_16x16x32_bf16(kf0, qf[c], st0, 0, 0, 0);
          st1 = __builtin_amdgcn_mfma_f32_16x16x32_bf16(kf1, qf[c], st1, 0, 0, 0);
        }
        __builtin_amdgcn_s_setprio(0);
        float p[2][4];
        float pm = -3e30f;
#pragma unroll
        for (int t = 0; t < 2; t++)
#pragma unroll
          for (int e = 0; e < 4; e++) {
            int key = key0 + t * 16 + 4 * g + e;
            float sv = (t == 0 ? st0[e] : st1[e]);  // scale pre-folded into Q
            sv = (key <= qi && key > qi - 1024) ? sv : -2e30f;  // window mask
            p[t][e] = sv;
            pm = fmaxf(pm, sv);
          }
        pm = fmaxf(pm, __shfl_xor(pm, 16));
        pm = fmaxf(pm, __shfl_xor(pm, 32));
        // defer-max: skip O-rescale when max didn't grow by >8 (exp2 headroom 2^8)
        if (!__all(pm <= m + 8.0f)) {
          float newm = fmaxf(m, pm);
          float f = exp2f(m - newm);
          m = newm;
          lsum *= f;
#pragma unroll
          for (int i = 0; i < 16; i++) {
            o[i][0] *= f; o[i][1] *= f; o[i][2] *= f; o[i][3] *= f;
          }
        }
        float ps = 0.0f;
#pragma unroll
        for (int t = 0; t < 2; t++)
#pragma unroll
          for (int e = 0; e < 4; e++) {
            float pe = exp2f(p[t][e] - m);
            p[t][e] = pe;
            ps += pe;
          }
        ps += __shfl_xor(ps, 16);
        ps += __shfl_xor(ps, 32);
        lsum += ps;
        short pk[8];
#pragma unroll
        for (int e2 = 0; e2 < 8; e2++) {
          int srcl = r + 16 * (2 * (g & 1) + (e2 >> 2));
          float a0 = __shfl(p[0][e2 & 3], srcl);
          float a1 = __shfl(p[1][e2 & 3], srcl);
          pk[e2] = (short)f2bf((g < 2) ? a0 : a1);
        }
        bf16x8 pf = {pk[0], pk[1], pk[2], pk[3], pk[4], pk[5], pk[6], pk[7]};
        int yx = ((g ^ ((r >> 1) & 3)) << 3);
        __builtin_amdgcn_s_setprio(1);
#pragma unroll
        for (int c2 = 0; c2 < 16; c2++) {  // O^T += V^T . P^T, swizzled LDS reads
          bf16x8 vf = *(const bf16x8*)(vc + (c2 * 16 + r) * 32 + yx);
          o[c2] = __builtin_amdgcn_mfma_f32_16x16x32_bf16(vf, pf, o[c2], 0, 0, 0);
        }
        __builtin_amdgcn_s_setprio(0);
      }
    }
    __syncthreads();
    cur ^= 1;
  }
  float linv = 1.0f / lsum;
  unsigned short* arow = attn + ((size_t)(b * S_LEN) + q0 + ww * 16 + r) * (HQ_N * HD_N) + h * HD_N;
#pragma unroll
  for (int c2 = 0; c2 < 16; c2++) {
    unsigned int w0 = (unsigned)f2bf(o[c2][0] * linv) | ((unsigned)f2bf(o[c2][1] * linv) << 16);
    unsigned int w1 = (unsigned)f2bf(o[c2][2] * linv) | ((unsigned)f2bf(o[c2][3] * linv) << 16);
    *(unsigned int*)(arow + c2 * 16 + 4 * g) = w0;
    *(unsigned int*)(arow + c2 * 16 + 4 * g + 2) = w1;
  }
}

extern "C" void kernel_launch(void* const* d_in, const int* in_sizes, int n_in,
                              void* d_out, int out_size, void* d_ws, size_t ws_size,
                              hipStream_t stream) {
  const float* hid  = (const float*)d_in[0];
  const float* cosb = (const float*)d_in[1];
  const float* sinb = (const float*)d_in[2];
  const float* Wq   = (const float*)d_in[4];
  const float* Wk   = (const float*)d_in[5];
  const float* Wv   = (const float*)d_in[6];
  const float* Wo   = (const float*)d_in[7];
  const float* qw   = (const float*)d_in[8];
  const float* kw   = (const float*)d_in[9];

  char* ws = (char*)d_ws;
  unsigned short* Xbf   = (unsigned short*)(ws + 0);            // 4096x2560 bf16
  unsigned short* Wcat  = (unsigned short*)(ws + 20971520);     // 4096x2560 bf16
  unsigned short* Wob   = (unsigned short*)(ws + 41943040);     // 2560x2048 bf16
  unsigned short* QKV   = (unsigned short*)(ws + 52428800);     // 4096x4096 bf16
  unsigned short* qbuf  = (unsigned short*)(ws + 85983232);     // 2*8*2048*256
  unsigned short* kbuf  = (unsigned short*)(ws + 102760448);    // 2*4*2048*256 (tiled)
  unsigned short* vbuf  = (unsigned short*)(ws + 111149056);    // 2*4*2048*256 (tiled)
  unsigned short* attnb = (unsigned short*)(ws + 119537664);    // 4096x2048 bf16
  // total: 136,314,880 B

  // 1) merged casts (one launch)
  cvt_all_kernel<<<25600, 256, 0, stream>>>(hid, Wq, Wk, Wv, Wo, Xbf, Wcat, Wob);
  // 2) fused QKV projection: QKV = X @ Wcat^T  (grid 16x16 = 256 blocks, NT=40)
  gemm8p<1><<<256, 512, 0, stream>>>(Xbf, Wcat, QKV, 4096, 4096, 2560, 16);
  // 3) RMSNorm + RoPE (Q pre-scaled; K/V written tiled+swizzled for attn LDS staging)
  rms_rope_kernel<<<16384, 256, 0, stream>>>(QKV, cosb, sinb, qw, kw, qbuf, kbuf, vbuf);
  // 4) sliding-window flash attention (GQA-paired, 256 blocks x 512 thr)
  attn_kernel<<<256, 512, 0, stream>>>(qbuf, kbuf, vbuf, attnb);
  // 5) output projection: d_out = attn @ Wo^T (fp32 out, grid 10x16 = 160 blocks, NT=32)
  gemm8p<0><<<160, 512, 0, stream>>>(attnb, Wob, (float*)d_out, 4096, 2560, 2048, 10);
}